// Round 4
// baseline (317.829 us; speedup 1.0000x reference)
//
#include <hip/hip_runtime.h>
#include <hip/hip_fp16.h>
#include <math.h>

// n=16, C=512, c4=128, qk=16, H=W=32, L=1024. fp32 in/out.
// conv (K=2304, mean-channels factored out analytically) + fused flash attention
// + value-proj, all matmuls on MFMA.
//
// ws layout (float offsets):
#define OFF_COR   0u          // cor   [16][512][9] f32 (mean-channel conv contribution)
#define OFF_PVH   2097152u    // pvh   [16][128][1024] f16
#define OFF_Y     3145728u    // y     [16][512][1024] f32
                              //   UNION: xT f16 [16][1024][512] (dead before convmm)
#define OFF_CATP  11534336u   // catT_p[16][1156][256] bf16 (pixel-major, 34x34 zero-padded)
#define OFF_QH    15085568u   // qh    [2][16][1024][16] f16
#define OFF_KH    15347712u   // kh    [2][16][1024][16] f16
#define OFF_POOL  16134144u   // pool  [16][512][20] f32
#define OFF_FEAT  16297984u   // feat  [16][128][20] f32
#define OFF_AW    16338944u   // Aw    [512][2304] bf16 (k' = g*576 + tap*64 + i, ic=128+g*64+i)
#define OFF_MEANS 17223680u   // means [16][128] f32
#define OFF_STAT  17225728u   // stats [512][2] f32
#define OFF_VWH   17226752u   // vwh   [128][512] f16

typedef __bf16 bf16x8 __attribute__((ext_vector_type(8)));
typedef _Float16 f16x8 __attribute__((ext_vector_type(8)));
typedef _Float16 f16x4 __attribute__((ext_vector_type(4)));
typedef float f32x4 __attribute__((ext_vector_type(4)));

__device__ __forceinline__ unsigned short f2bf(float f) {
  unsigned int u = __float_as_uint(f);
  unsigned int r = u + 0x7fff + ((u >> 16) & 1);   // RNE
  return (unsigned short)(r >> 16);
}

__device__ __forceinline__ unsigned short f2h(float f) {
  union { _Float16 h; unsigned short u; } cv;
  cv.h = (_Float16)f;
  return cv.u;
}

__device__ __forceinline__ void gload_lds16(const void* g, void* l) {
  __builtin_amdgcn_global_load_lds(
      (const __attribute__((address_space(1))) unsigned int*)g,
      (__attribute__((address_space(3))) unsigned int*)l, 16, 0, 0);
}

// ---------------- pooling: pooled4 (8x8 blocks) + pooled2 derived ----------------
__global__ __launch_bounds__(256) void pool_kernel(const float* __restrict__ x,
                                                   float* __restrict__ pool) {
  int b = blockIdx.x;            // n*512 + c
  int t = threadIdx.x;
  const float4* xp = (const float4*)(x + (size_t)b * 1024);
  float4 v = xp[t];
  float s4 = v.x + v.y + v.z + v.w;
  __shared__ float sm[256];
  __shared__ float p4s[16];
  sm[t] = s4;
  __syncthreads();
  if (t < 16) {
    int br = t >> 2, bc = t & 3;
    float s = 0.f;
#pragma unroll
    for (int rr = 0; rr < 8; ++rr) {
      int base = br * 64 + rr * 8 + bc * 2;
      s += sm[base] + sm[base + 1];
    }
    s *= (1.f / 64.f);
    p4s[t] = s;
    pool[(size_t)b * 20 + t] = s;
  }
  __syncthreads();
  if (t < 4) {
    int i2 = t >> 1, j2 = t & 1;
    float s = (p4s[(2*i2)*4 + 2*j2]     + p4s[(2*i2)*4 + 2*j2 + 1] +
               p4s[(2*i2+1)*4 + 2*j2]   + p4s[(2*i2+1)*4 + 2*j2 + 1]) * 0.25f;
    pool[(size_t)b * 20 + 16 + t] = s;
  }
}

// ---------------- feat = rce_w[i] @ pooled_i + rce_b[i] (scales sz=2,4) ----------------
__global__ __launch_bounds__(64) void feat_kernel(const float* __restrict__ pool,
                                                  const float* __restrict__ rce_w,
                                                  const float* __restrict__ rce_b,
                                                  float* __restrict__ feat) {
  int o = blockIdx.x, n = blockIdx.y, t = threadIdx.x;
  float part[20];
#pragma unroll
  for (int j = 0; j < 20; ++j) part[j] = 0.f;
  for (int c = t; c < 512; c += 64) {
    const float* pl = pool + ((size_t)n * 512 + c) * 20;
    float w2 = rce_w[(size_t)(128 + o) * 512 + c];
    float w4 = rce_w[(size_t)(256 + o) * 512 + c];
#pragma unroll
    for (int j = 0; j < 4; ++j)  part[j]     += w2 * pl[16 + j];
#pragma unroll
    for (int j = 0; j < 16; ++j) part[4 + j] += w4 * pl[j];
  }
  __shared__ float red[64][20];
#pragma unroll
  for (int j = 0; j < 20; ++j) red[t][j] = part[j];
  __syncthreads();
  if (t < 20) {
    float s = 0.f;
    for (int i = 0; i < 64; ++i) s += red[i][t];
    s += (t < 4) ? rce_b[128 + o] : rce_b[256 + o];
    feat[((size_t)n * 128 + o) * 20 + t] = s;
  }
}

// ------------- q/k fields, f16, layout [s][n][l][16] for MFMA attention -------------
__global__ __launch_bounds__(256) void qk2_kernel(const float* __restrict__ feat,
                                                  const float* __restrict__ q_w,
                                                  const float* __restrict__ q_b,
                                                  const float* __restrict__ k_w,
                                                  const float* __restrict__ k_b,
                                                  unsigned short* __restrict__ qh,
                                                  unsigned short* __restrict__ kh) {
  int n = blockIdx.x, t = threadIdx.x;
  __shared__ float fL[128 * 20];
  __shared__ float GH[2][16][20];
  for (int idx = t; idx < 2560; idx += 256) fL[idx] = feat[(size_t)n * 2560 + idx];
  __syncthreads();
  for (int idx = t; idx < 640; idx += 256) {
    int which = idx / 320, rem = idx % 320, qc = rem / 20, j = rem % 20;
    const float* w = which ? k_w : q_w;
    float s = which ? k_b[qc] : q_b[qc];
    for (int c = 0; c < 128; ++c) s += w[qc * 128 + c] * fL[c * 20 + j];
    GH[which][qc][j] = s;
  }
  __syncthreads();
  for (int it = 0; it < 16; ++it) {
    int row = t + 256 * it;              // 4096 rows: [s][which][l]
    int l = row & 1023, which = (row >> 10) & 1, s = row >> 11;
    int ry = l >> 5, cx = l & 31;
    int t0, t1, t2, t3;
    float w0, w1, w2, w3;
    if (s == 0) {
      float a = ry * (1.0f / 31.0f), b = cx * (1.0f / 31.0f);
      t0 = 0; t1 = 1; t2 = 2; t3 = 3;
      w0 = (1.f - a) * (1.f - b); w1 = (1.f - a) * b;
      w2 = a * (1.f - b);         w3 = a * b;
    } else {
      float pr = ry * (3.0f / 31.0f);
      int lr = (int)pr; if (lr > 2) lr = 2;
      float fr = pr - (float)lr;
      float pc = cx * (3.0f / 31.0f);
      int lc = (int)pc; if (lc > 2) lc = 2;
      float fc = pc - (float)lc;
      int base = 4 + lr * 4 + lc;
      t0 = base; t1 = base + 1; t2 = base + 4; t3 = base + 5;
      w0 = (1.f - fr) * (1.f - fc); w1 = (1.f - fr) * fc;
      w2 = fr * (1.f - fc);         w3 = fr * fc;
    }
    float val[16];
#pragma unroll
    for (int qc = 0; qc < 16; ++qc) {
      const float* G = GH[which][qc];
      val[qc] = w0 * G[t0] + w1 * G[t1] + w2 * G[t2] + w3 * G[t3];
    }
    unsigned short* dst = (which ? kh : qh) + (((size_t)(s * 16 + n) * 1024 + l) * 16);
#pragma unroll
    for (int u = 0; u < 4; ++u)
      *(ushort4*)(dst + 4 * u) = make_ushort4(f2h(val[4*u]), f2h(val[4*u+1]),
                                              f2h(val[4*u+2]), f2h(val[4*u+3]));
  }
}

// ---------------- xT[n][l][c] = f16(x[n][c][l])  (LDS tile transpose) ----------------
__global__ __launch_bounds__(256) void xcast_kernel(const float* __restrict__ x,
                                                    unsigned short* __restrict__ xT) {
  int lt = blockIdx.x, ct = blockIdx.y, n = blockIdx.z;
  int l0 = lt * 64, c0 = ct * 64, t = threadIdx.x;
  __shared__ float tile[64 * 65];
#pragma unroll
  for (int i = 0; i < 16; ++i) {
    int idx = t + 256 * i;
    int c = idx >> 6, l = idx & 63;
    tile[c * 65 + l] = x[((size_t)n * 512 + c0 + c) * 1024 + l0 + l];
  }
  __syncthreads();
#pragma unroll
  for (int i = 0; i < 16; ++i) {
    int idx = t + 256 * i;
    int l = idx >> 6, c = idx & 63;
    xT[((size_t)n * 1024 + l0 + l) * 512 + c0 + c] = f2h(tile[c * 65 + l]);
  }
}

// ---------------- vwh = f16(value_w) ----------------
__global__ __launch_bounds__(256) void vwcast_kernel(const float* __restrict__ vw,
                                                     unsigned short* __restrict__ vwh) {
  int i = blockIdx.x * 256 + threadIdx.x;
  vwh[i] = f2h(vw[i]);
}

// ------------- value-proj GEMM (f16 MFMA): pvh[c,l] = f16(sum_k vwh[c,k] xT[n][l][k] + vb) -------------
__global__ __launch_bounds__(256) void pvmm2_kernel(const unsigned short* __restrict__ vwh,
                                                    const unsigned short* __restrict__ xT,
                                                    const float* __restrict__ vb,
                                                    unsigned short* __restrict__ pvh) {
  int l0 = blockIdx.x * 64;
  int n = blockIdx.y;
  int t = threadIdx.x, lane = t & 63, wv = t >> 6;
  int wm = (wv & 1) * 64, wn = (wv >> 1) * 32;

  __shared__ short Asm[128 * 32];
  __shared__ short Bsm[64 * 32];

  int ar0 = t >> 2,        aq0 = (t & 3) ^ ((ar0 >> 1) & 3);
  int idx1 = t + 256; int ar1 = idx1 >> 2, aq1 = (idx1 & 3) ^ ((ar1 >> 1) & 3);
  int br  = t >> 2,        bq  = (t & 3) ^ ((br >> 1) & 3);
  const unsigned short* Ab0 = vwh + (size_t)ar0 * 512 + aq0 * 8;
  const unsigned short* Ab1 = vwh + (size_t)ar1 * 512 + aq1 * 8;
  const unsigned short* Bb  = xT + ((size_t)n * 1024 + l0 + br) * 512 + bq * 8;
  char* ldsA = (char*)Asm;
  char* ldsB = (char*)Bsm;
  int wvoff = wv * 1024;
  int r15 = lane & 15, kg = lane >> 4;
  int kq = kg ^ ((r15 >> 1) & 3);

  f32x4 acc[4][2];
#pragma unroll
  for (int i = 0; i < 4; ++i)
#pragma unroll
    for (int j = 0; j < 2; ++j) acc[i][j] = (f32x4){0.f, 0.f, 0.f, 0.f};

  for (int k0 = 0; k0 < 512; k0 += 32) {
    __syncthreads();
    gload_lds16(Ab0 + k0, ldsA + wvoff);
    gload_lds16(Ab1 + k0, ldsA + 4096 + wvoff);
    gload_lds16(Bb + k0,  ldsB + wvoff);
    __syncthreads();
    f16x8 af[4], bfr[2];
#pragma unroll
    for (int mt2 = 0; mt2 < 4; ++mt2)
      af[mt2] = *(const f16x8*)&Asm[(wm + mt2 * 16 + r15) * 32 + kq * 8];
#pragma unroll
    for (int nt2 = 0; nt2 < 2; ++nt2)
      bfr[nt2] = *(const f16x8*)&Bsm[(wn + nt2 * 16 + r15) * 32 + kq * 8];
#pragma unroll
    for (int mt2 = 0; mt2 < 4; ++mt2)
#pragma unroll
      for (int nt2 = 0; nt2 < 2; ++nt2)
        acc[mt2][nt2] = __builtin_amdgcn_mfma_f32_16x16x32_f16(af[mt2], bfr[nt2], acc[mt2][nt2], 0, 0, 0);
  }

  int c_lo = wm + (lane >> 4) * 4;
  int l_lo = wn + (lane & 15);
#pragma unroll
  for (int mt2 = 0; mt2 < 4; ++mt2)
#pragma unroll
    for (int nt2 = 0; nt2 < 2; ++nt2) {
      int l = l0 + l_lo + nt2 * 16;
#pragma unroll
      for (int r = 0; r < 4; ++r) {
        int c = c_lo + mt2 * 16 + r;
        pvh[((size_t)n * 128 + c) * 1024 + l] = f2h(acc[mt2][nt2][r] + vb[c]);
      }
    }
}

// ---------------- means[n][c] = mean_l pvh[n][c][l]  (sz=1 branch is constant) ----------------
__global__ __launch_bounds__(256) void mean_kernel(const unsigned short* __restrict__ pvh,
                                                   float* __restrict__ means) {
  int c = blockIdx.x, n = blockIdx.y, t = threadIdx.x;
  f16x4 v = ((const f16x4*)(pvh + ((size_t)n * 128 + c) * 1024))[t];
  float s = (float)v[0] + (float)v[1] + (float)v[2] + (float)v[3];
  for (int o = 32; o > 0; o >>= 1) s += __shfl_down(s, o);
  __shared__ float wsum[4];
  if ((t & 63) == 0) wsum[t >> 6] = s;
  __syncthreads();
  if (t == 0) means[n * 128 + c] = (wsum[0] + wsum[1] + wsum[2] + wsum[3]) * (1.f / 1024.f);
}

// ---- basecor: cor[n][oc][a*3+b] = sum over valid taps of S[ky][kx],
//      S[ky][kx] = sum_{c<128} means[n][c] * fw[oc][c][ky][kx].
//      a/b: 0 = top/left edge (ky/kx=0 cut), 1 = interior, 2 = bottom/right edge.
__global__ __launch_bounds__(64) void basecor_kernel(const float* __restrict__ means,
                                                     const float* __restrict__ fw,
                                                     float* __restrict__ cor) {
  int oc = blockIdx.x, n = blockIdx.y, t = threadIdx.x;
  float S[9];
#pragma unroll
  for (int j = 0; j < 9; ++j) S[j] = 0.f;
  for (int c = t; c < 128; c += 64) {
    float m = means[n * 128 + c];
    const float* wp = fw + (size_t)oc * 3456 + c * 9;
#pragma unroll
    for (int j = 0; j < 9; ++j) S[j] += m * wp[j];
  }
  __shared__ float red[64][9];
  __shared__ float Sf[9];
#pragma unroll
  for (int j = 0; j < 9; ++j) red[t][j] = S[j];
  __syncthreads();
  if (t < 9) {
    float s = 0.f;
    for (int i = 0; i < 64; ++i) s += red[i][t];
    Sf[t] = s;
  }
  __syncthreads();
  if (t < 9) {
    int a = t / 3, b = t % 3;
    float s = 0.f;
#pragma unroll
    for (int ky = 0; ky < 3; ++ky) {
      if ((a == 0 && ky == 0) || (a == 2 && ky == 2)) continue;
#pragma unroll
      for (int kx = 0; kx < 3; ++kx) {
        if ((b == 0 && kx == 0) || (b == 2 && kx == 2)) continue;
        s += Sf[ky * 3 + kx];
      }
    }
    cor[((size_t)n * 512 + oc) * 9 + t] = s;
  }
}

// ---- fillcat: zero the 132 border rows of each image (256 ch each) ----
__global__ __launch_bounds__(128) void fillcat_kernel(unsigned short* __restrict__ catp) {
  int b = blockIdx.x;            // n*132 + e
  int n = b / 132, e = b % 132;
  int py, px;
  if (e < 34)       { py = 0;          px = e; }
  else if (e < 68)  { py = 33;         px = e - 34; }
  else if (e < 100) { py = e - 68 + 1; px = 0; }
  else              { py = e - 100 + 1; px = 33; }
  unsigned int* row = (unsigned int*)(catp + ((size_t)n * 1156 + py * 34 + px) * 256);
  row[threadIdx.x] = 0u;         // 128 threads x 4 B = 512 B = full row
}

// ---------------- weight reorder+cast: Aw[oc][g*576 + tap*64 + i], ic = 128+g*64+i ----------------
__global__ __launch_bounds__(256) void wcast_kernel(const float* __restrict__ fw,
                                                    unsigned short* __restrict__ Aw) {
  int oc = blockIdx.x, t = threadIdx.x;
  for (int j = t; j < 2304; j += 256) {
    int g = j / 576, r = j % 576;
    int tap = r >> 6, i = r & 63;
    Aw[(size_t)oc * 2304 + j] =
        f2bf(fw[(size_t)oc * 3456 + (size_t)(128 + g * 64 + i) * 9 + tap]);
  }
}

// ------------- fused flash attention (MFMA QK^T + MFMA PV, no P in HBM) -------------
__global__ __launch_bounds__(256) void fattn_kernel(const unsigned short* __restrict__ qh,
                                                    const unsigned short* __restrict__ kh,
                                                    const unsigned short* __restrict__ pvh,
                                                    unsigned short* __restrict__ catp) {
  int m0 = blockIdx.x * 64;
  int n = blockIdx.y, sc = blockIdx.z;
  int t = threadIdx.x, lane = t & 63, wv = t >> 6;
  int wc = (wv >> 1) * 64;      // c base (0/64)
  int wm2 = (wv & 1) * 32;      // m base within block tile (0/32)
  int r15 = lane & 15, kg = lane >> 4;
  int kq = kg ^ ((r15 >> 1) & 3);

  const unsigned short* qb  = qh + ((size_t)(sc * 16 + n) * 1024 + m0 + wv * 16) * 16;
  const unsigned short* kb  = kh + ((size_t)(sc * 16 + n) * 1024) * 16;
  const unsigned short* pvb = pvh + (size_t)n * 128 * 1024;

  __shared__ short PVs[2 * 128 * 32];
  __shared__ _Float16 Us[64 * 72];
  __shared__ float rsum[64];

  f16x8 zf = {0, 0, 0, 0, 0, 0, 0, 0};
  f16x8 qa = (kg < 2) ? *(const f16x8*)(qb + r15 * 16 + kg * 8) : zf;

  int prow = t >> 2;
  int aq = (t & 3) ^ ((prow >> 1) & 3);
  const unsigned short* Pb0 = pvb + (size_t)prow * 1024 + aq * 8;
  const unsigned short* Pb1 = pvb + (size_t)(prow + 64) * 1024 + aq * 8;
  char* ldsPV = (char*)PVs;
  int wvoff = wv * 1024;

  f32x4 acc[4][2];
#pragma unroll
  for (int i = 0; i < 4; ++i)
#pragma unroll
    for (int j = 0; j < 2; ++j) acc[i][j] = (f32x4){0.f, 0.f, 0.f, 0.f};
  float rs[4] = {0.f, 0.f, 0.f, 0.f};

  for (int it = 0; it < 16; ++it) {
    int l0 = it * 64;
    __syncthreads();
    gload_lds16(Pb0 + l0,      ldsPV + wvoff);
    gload_lds16(Pb1 + l0,      ldsPV + 4096 + wvoff);
    gload_lds16(Pb0 + l0 + 32, ldsPV + 8192 + wvoff);
    gload_lds16(Pb1 + l0 + 32, ldsPV + 12288 + wvoff);

    f32x4 sacc[4];
#pragma unroll
    for (int lt = 0; lt < 4; ++lt) {
      f16x8 kbf = (kg < 2)
        ? *(const f16x8*)(kb + (size_t)(l0 + lt * 16 + r15) * 16 + kg * 8) : zf;
      sacc[lt] = __builtin_amdgcn_mfma_f32_16x16x32_f16(qa, kbf, (f32x4){0.f,0.f,0.f,0.f}, 0, 0, 0);
    }
#pragma unroll
    for (int lt = 0; lt < 4; ++lt)
#pragma unroll
      for (int r = 0; r < 4; ++r) {
        float e = __expf(sacc[lt][r]);
        Us[(wv * 16 + kg * 4 + r) * 72 + lt * 16 + r15] = (_Float16)e;
        rs[r] += e;
      }
    __syncthreads();

#pragma unroll
    for (int ks = 0; ks < 2; ++ks) {
      f16x8 bfr[2];
#pragma unroll
      for (int nt = 0; nt < 2; ++nt)
        bfr[nt] = *(const f16x8*)&Us[(wm2 + nt * 16 + r15) * 72 + ks * 32 + kg * 8];
#pragma unroll
      for (int ct = 0; ct < 4; ++ct) {
        f16x8 af = *(const f16x8*)&PVs[ks * 4096 + (wc + ct * 16 + r15) * 32 + kq * 8];
#pragma unroll
        for (int nt = 0; nt < 2; ++nt)
          acc[ct][nt] = __builtin_amdgcn_mfma_f32_16x16x32_f16(af, bfr[nt], acc[ct][nt], 0, 0, 0);
      }
    }
  }

#pragma unroll
  for (int r = 0; r < 4; ++r) {
    rs[r] += __shfl_xor(rs[r], 1);
    rs[r] += __shfl_xor(rs[r], 2);
    rs[r] += __shfl_xor(rs[r], 4);
    rs[r] += __shfl_xor(rs[r], 8);
  }
  if (r15 == 0) {
#pragma unroll
    for (int r = 0; r < 4; ++r) rsum[wv * 16 + kg * 4 + r] = rs[r];
  }
  __syncthreads();

#pragma unroll
  for (int nt = 0; nt < 2; ++nt) {
    float inv = 1.f / rsum[wm2 + nt * 16 + r15];
    int pix = m0 + wm2 + nt * 16 + r15;
    unsigned short* ob = catp + ((size_t)n * 1156 + ((pix >> 5) + 1) * 34 + (pix & 31) + 1) * 256
                       + sc * 128 + wc + kg * 4;
#pragma unroll
    for (int ct = 0; ct < 4; ++ct) {
      ushort4 o = make_ushort4(f2bf(acc[ct][nt][0] * inv), f2bf(acc[ct][nt][1] * inv),
                               f2bf(acc[ct][nt][2] * inv), f2bf(acc[ct][nt][3] * inv));
      *(ushort4*)(ob + ct * 16) = o;
    }
  }
}

// ---------------- fusion conv as implicit GEMM (bf16 MFMA, K=2304) ----------------
// Barrier-free inner loop: A (weights) streams global->VGPR double-buffered one
// tap ahead (tap-major Aw layout makes each fragment a plain 16B load, no LDS);
// B halo persistent in LDS, double-buffered per 64-ic group (2 x 26 KB), staged
// at the start of the previous group. Only 3 vmcnt(0)+s_barrier pairs per block
// (group boundaries) - waves self-pipeline: prefetch-A || ds_read-B || MFMA.
// mean-channel contribution added from cor[n][oc][3x3] in the epilogue.
__global__ __launch_bounds__(256) void convmm_kernel(const unsigned short* __restrict__ Aw,
                                                     const unsigned short* __restrict__ catp,
                                                     const float* __restrict__ cor,
                                                     float* __restrict__ y) {
  int ntile = blockIdx.x;
  int n = ntile >> 3, y0 = (ntile & 7) * 4;
  int m0 = blockIdx.y * 128;
  int t = threadIdx.x;
  int lane = t & 63, wv = t >> 6;
  int wm = (wv & 1) * 64, wn = (wv >> 1) * 64;

  __shared__ short Bimg[2 * 208 * 64];      // [buf][208 px][64 ic], chunk-swizzled, 52 KB
  char* ldsB = (char*)Bimg;

  // ---- B halo staging: lane covers (px = j*8 + lane/8, chunk = lane%8); source
  // chunk pre-swizzled by px so tap-shifted reads land conflict-free ----
  const unsigned short* cb = catp + ((size_t)n * 1156 + (size_t)y0 * 34) * 256;
  int bpx = lane >> 3;
  int bch = (lane & 7) ^ (bpx & 7);

  int r15 = lane & 15, kg = lane >> 4;

  // per-lane A fragment base: row = m0+wm+r15 (+mt*16), k = g*576+tap*64+c*32+kg*8
  const unsigned short* Ap = Aw + (size_t)(m0 + wm + r15) * 2304 + kg * 8;

  // per-nt pixel base within the halo strip (row r -> +34, col x -> +1)
  int pxl[4];
#pragma unroll
  for (int nt = 0; nt < 4; ++nt) {
    int pn = wn + nt * 16 + r15;
    pxl[nt] = (pn >> 5) * 34 + (pn & 31);
  }

  f32x4 acc[4][4];
#pragma unroll
  for (int i = 0; i < 4; ++i)
#pragma unroll
    for (int j = 0; j < 4; ++j) acc[i][j] = (f32x4){0.f, 0.f, 0.f, 0.f};

  bf16x8 Ar[2][8];   // double-buffered A fragments (parity = (g + tap) & 1)

  // prologue: stage B(g=0) -> buf0; prefetch A(g=0,tap=0) -> Ar[0]
  for (int j = wv; j < 26; j += 4)
    gload_lds16(cb + (size_t)(j * 8 + bpx) * 256 + bch * 8, ldsB + j * 1024);
#pragma unroll
  for (int c = 0; c < 2; ++c)
#pragma unroll
    for (int mt = 0; mt < 4; ++mt)
      Ar[0][c * 4 + mt] = *(const bf16x8*)(Ap + (size_t)mt * 16 * 2304 + c * 32);
  asm volatile("s_waitcnt vmcnt(0)" ::: "memory");
  __builtin_amdgcn_s_barrier();

#pragma unroll 2
  for (int g = 0; g < 4; ++g) {
    int gpar = g & 1;
    // stage next group's B halo early (overlaps with this group's 9 taps)
    if (g < 3) {
      for (int j = wv; j < 26; j += 4)
        gload_lds16(cb + (size_t)(j * 8 + bpx) * 256 + (g + 1) * 64 + bch * 8,
                    ldsB + (gpar ^ 1) * 26624 + j * 1024);
    }
    const unsigned short* Agbase = Ap + g * 576;
#pragma unroll
    for (int tap = 0; tap < 9; ++tap) {
      int par = (g + tap) & 1;     // static: g unrolled x2, tap fully unrolled
      // prefetch next tap's A fragments
      if (!(g == 3 && tap == 8)) {
        const unsigned short* An = (tap == 8) ? (Agbase + 576) : (Agbase + (tap + 1) * 64);
#pragma unroll
        for (int c = 0; c < 2; ++c)
#pragma unroll
          for (int mt = 0; mt < 4; ++mt)
            Ar[par ^ 1][c * 4 + mt] = *(const bf16x8*)(An + (size_t)mt * 16 * 2304 + c * 32);
      }
      int sy = tap / 3;
      int toff = sy * 34 + (tap - sy * 3);
      bf16x8 bfv[2][4];
#pragma unroll
      for (int c = 0; c < 2; ++c)
#pragma unroll
        for (int nt = 0; nt < 4; ++nt) {
          int px = pxl[nt] + toff;
          int lch = (c * 4 + kg) ^ (px & 7);
          bfv[c][nt] = *(const bf16x8*)&Bimg[gpar * 13312 + px * 64 + lch * 8];
        }
#pragma unroll
      for (int c = 0; c < 2; ++c)
#pragma unroll
        for (int mt = 0; mt < 4; ++mt)
#pragma unroll
          for (int nt = 0; nt < 4; ++nt)
            acc[mt][nt] = __builtin_amdgcn_mfma_f32_16x16x32_bf16(
                Ar[par][c * 4 + mt], bfv[c][nt], acc[mt][nt], 0, 0, 0);
    }
    if (g < 3) {
      // own B(g+1)/A loads drained, then all waves' LDS writes visible
      asm volatile("s_waitcnt vmcnt(0)" ::: "memory");
      __builtin_amdgcn_s_barrier();
    }
  }

  int pixbase = (ntile & 7) * 128 + wn + (lane & 15);
  int ocbase = m0 + wm + (lane >> 4) * 4;
#pragma unroll
  for (int mt = 0; mt < 4; ++mt)
#pragma unroll
    for (int nt = 0; nt < 4; ++nt) {
      int oc = ocbase + mt * 16;
      int pix = pixbase + nt * 16;
      int py = pix >> 5, px = pix & 31;
      int yc = (py == 0) ? 0 : ((py == 31) ? 2 : 1);
      int xc = (px == 0) ? 0 : ((px == 31) ? 2 : 1);
      const float* cp = cor + ((size_t)n * 512 + oc) * 9 + yc * 3 + xc;
      float* yp = y + ((size_t)n * 512 + oc) * 1024 + pix;
#pragma unroll
      for (int r = 0; r < 4; ++r) yp[(size_t)r * 1024] = acc[mt][nt][r] + cp[(size_t)r * 9];
    }
}

// ---------------- BN batch stats per channel ----------------
__global__ __launch_bounds__(256) void bnstat_kernel(const float* __restrict__ y,
                                                     const float* __restrict__ bn_scale,
                                                     const float* __restrict__ bn_bias,
                                                     float* __restrict__ stats) {
  int oc = blockIdx.x, t = threadIdx.x;
  float s = 0.f, ss = 0.f;
  for (int n = 0; n < 16; ++n) {
    float4 v = ((const float4*)(y + ((size_t)n * 512 + oc) * 1024))[t];
    s  += v.x + v.y + v.z + v.w;
    ss += v.x * v.x + v.y * v.y + v.z * v.z + v.w * v.w;
  }
  for (int o = 32; o > 0; o >>= 1) {
    s  += __shfl_down(s, o);
    ss += __shfl_down(ss, o);
  }
  __shared__ float rs[4], rss[4];
  if ((t & 63) == 0) { rs[t >> 6] = s; rss[t >> 6] = ss; }
  __syncthreads();
  if (t == 0) {
    float S = rs[0] + rs[1] + rs[2] + rs[3];
    float SS = rss[0] + rss[1] + rss[2] + rss[3];
    float mean = S * (1.f / 16384.f);
    float var = SS * (1.f / 16384.f) - mean * mean;
    float se = bn_scale[oc] / sqrtf(var + 1e-5f);
    stats[oc * 2] = se;
    stats[oc * 2 + 1] = bn_bias[oc] - mean * se;
  }
}

// ---------------- normalize + relu + gamma*y + x ----------------
__global__ __launch_bounds__(256) void final_kernel(const float* __restrict__ y,
                                                    const float* __restrict__ x,
                                                    const float* __restrict__ stats,
                                                    const float* __restrict__ gamma,
                                                    float* __restrict__ outp) {
  int b = blockIdx.x;
  int c = b & 511;
  int t = threadIdx.x;
  float se = stats[c * 2], sh = stats[c * 2 + 1], g = gamma[0];
  float4 yv = ((const float4*)(y + (size_t)b * 1024))[t];
  float4 xv = ((const float4*)(x + (size_t)b * 1024))[t];
  float4 o;
  o.x = g * fmaxf(yv.x * se + sh, 0.f) + xv.x;
  o.y = g * fmaxf(yv.y * se + sh, 0.f) + xv.y;
  o.z = g * fmaxf(yv.z * se + sh, 0.f) + xv.z;
  o.w = g * fmaxf(yv.w * se + sh, 0.f) + xv.w;
  ((float4*)(outp + (size_t)b * 1024))[t] = o;
}

extern "C" void kernel_launch(void* const* d_in, const int* in_sizes, int n_in,
                              void* d_out, int out_size, void* d_ws, size_t ws_size,
                              hipStream_t stream) {
  const float* x        = (const float*)d_in[0];
  const float* rce_w    = (const float*)d_in[1];
  const float* rce_b    = (const float*)d_in[2];
  const float* q_w      = (const float*)d_in[3];
  const float* q_b      = (const float*)d_in[4];
  const float* k_w      = (const float*)d_in[5];
  const float* k_b      = (const float*)d_in[6];
  const float* value_w  = (const float*)d_in[7];
  const float* value_b  = (const float*)d_in[8];
  const float* fw       = (const float*)d_in[9];
  const float* bn_scale = (const float*)d_in[10];
  const float* bn_bias  = (const float*)d_in[11];
  const float* gamma    = (const float*)d_in[12];

  float* ws    = (float*)d_ws;
  float* cor   = ws + OFF_COR;
  unsigned short* pvh = (unsigned short*)(ws + OFF_PVH);
  float* ybuf  = ws + OFF_Y;
  unsigned short* xTbuf = (unsigned short*)(ws + OFF_Y);  // union: dead before convmm
  unsigned short* catp = (unsigned short*)(ws + OFF_CATP);
  unsigned short* qh   = (unsigned short*)(ws + OFF_QH);
  unsigned short* kh   = (unsigned short*)(ws + OFF_KH);
  float* pool  = ws + OFF_POOL;
  float* feat  = ws + OFF_FEAT;
  unsigned short* Aw = (unsigned short*)(ws + OFF_AW);
  float* means = ws + OFF_MEANS;
  float* stats = ws + OFF_STAT;
  unsigned short* vwh = (unsigned short*)(ws + OFF_VWH);
  float* outp  = (float*)d_out;

  hipLaunchKernelGGL(pool_kernel,    dim3(8192),       dim3(256), 0, stream, x, pool);
  hipLaunchKernelGGL(feat_kernel,    dim3(128, 16),    dim3(64),  0, stream, pool, rce_w, rce_b, feat);
  hipLaunchKernelGGL(qk2_kernel,     dim3(16),         dim3(256), 0, stream, feat, q_w, q_b, k_w, k_b, qh, kh);
  hipLaunchKernelGGL(xcast_kernel,   dim3(16, 8, 16),  dim3(256), 0, stream, x, xTbuf);
  hipLaunchKernelGGL(vwcast_kernel,  dim3(256),        dim3(256), 0, stream, value_w, vwh);
  hipLaunchKernelGGL(pvmm2_kernel,   dim3(16, 16),     dim3(256), 0, stream, vwh, xTbuf, value_b, pvh);
  hipLaunchKernelGGL(mean_kernel,    dim3(128, 16),    dim3(256), 0, stream, pvh, means);
  hipLaunchKernelGGL(basecor_kernel, dim3(512, 16),    dim3(64),  0, stream, means, fw, cor);
  hipLaunchKernelGGL(fillcat_kernel, dim3(2112),       dim3(128), 0, stream, catp);
  hipLaunchKernelGGL(wcast_kernel,   dim3(512),        dim3(256), 0, stream, fw, Aw);
  hipLaunchKernelGGL(fattn_kernel,   dim3(16, 16, 2),  dim3(256), 0, stream, qh, kh, pvh, catp);
  hipLaunchKernelGGL(convmm_kernel,  dim3(128, 4),     dim3(256), 0, stream, Aw, catp, cor, ybuf);
  hipLaunchKernelGGL(bnstat_kernel,  dim3(512),        dim3(256), 0, stream, ybuf, bn_scale, bn_bias, stats);
  hipLaunchKernelGGL(final_kernel,   dim3(8192),       dim3(256), 0, stream, ybuf, x, stats, gamma, outp);
}

// Round 5
// 307.084 us; speedup vs baseline: 1.0350x; 1.0350x over previous
//
#include <hip/hip_runtime.h>
#include <hip/hip_fp16.h>
#include <math.h>

// n=16, C=512, c4=128, qk=16, H=W=32, L=1024. fp32 in/out.
// conv (K=2304, mean-channels factored out analytically) + fused flash attention
// + value-proj, all matmuls on MFMA.
//
// ws layout (float offsets):
#define OFF_COR   0u          // cor   [16][512][9] f32 (mean-channel conv contribution)
#define OFF_PVH   2097152u    // pvh   [16][128][1024] f16
#define OFF_Y     3145728u    // y     [16][512][1024] f32
                              //   UNION: xT f16 [16][1024][512] (dead before convmm)
#define OFF_CATP  11534336u   // catT_p[16][1156][256] bf16 (pixel-major, 34x34 zero-padded)
#define OFF_QH    15085568u   // qh    [2][16][1024][16] f16
#define OFF_KH    15347712u   // kh    [2][16][1024][16] f16
#define OFF_POOL  16134144u   // pool  [16][512][20] f32
#define OFF_FEAT  16297984u   // feat  [16][128][20] f32
#define OFF_AW    16338944u   // AwF   [32 mtile][4 g][9 tap][2 c][16 r][32 k] bf16 (fragment-major)
#define OFF_MEANS 17223680u   // means [16][128] f32
#define OFF_STAT  17225728u   // stats [512][2] f32
#define OFF_VWH   17226752u   // vwh   [128][512] f16

typedef __bf16 bf16x8 __attribute__((ext_vector_type(8)));
typedef _Float16 f16x8 __attribute__((ext_vector_type(8)));
typedef _Float16 f16x4 __attribute__((ext_vector_type(4)));
typedef float f32x4 __attribute__((ext_vector_type(4)));

__device__ __forceinline__ unsigned short f2bf(float f) {
  unsigned int u = __float_as_uint(f);
  unsigned int r = u + 0x7fff + ((u >> 16) & 1);   // RNE
  return (unsigned short)(r >> 16);
}

__device__ __forceinline__ unsigned short f2h(float f) {
  union { _Float16 h; unsigned short u; } cv;
  cv.h = (_Float16)f;
  return cv.u;
}

__device__ __forceinline__ void gload_lds16(const void* g, void* l) {
  __builtin_amdgcn_global_load_lds(
      (const __attribute__((address_space(1))) unsigned int*)g,
      (__attribute__((address_space(3))) unsigned int*)l, 16, 0, 0);
}

// ---------------- pooling: pooled4 (8x8 blocks) + pooled2 derived ----------------
__global__ __launch_bounds__(256) void pool_kernel(const float* __restrict__ x,
                                                   float* __restrict__ pool) {
  int b = blockIdx.x;            // n*512 + c
  int t = threadIdx.x;
  const float4* xp = (const float4*)(x + (size_t)b * 1024);
  float4 v = xp[t];
  float s4 = v.x + v.y + v.z + v.w;
  __shared__ float sm[256];
  __shared__ float p4s[16];
  sm[t] = s4;
  __syncthreads();
  if (t < 16) {
    int br = t >> 2, bc = t & 3;
    float s = 0.f;
#pragma unroll
    for (int rr = 0; rr < 8; ++rr) {
      int base = br * 64 + rr * 8 + bc * 2;
      s += sm[base] + sm[base + 1];
    }
    s *= (1.f / 64.f);
    p4s[t] = s;
    pool[(size_t)b * 20 + t] = s;
  }
  __syncthreads();
  if (t < 4) {
    int i2 = t >> 1, j2 = t & 1;
    float s = (p4s[(2*i2)*4 + 2*j2]     + p4s[(2*i2)*4 + 2*j2 + 1] +
               p4s[(2*i2+1)*4 + 2*j2]   + p4s[(2*i2+1)*4 + 2*j2 + 1]) * 0.25f;
    pool[(size_t)b * 20 + 16 + t] = s;
  }
}

// ---------------- feat = rce_w[i] @ pooled_i + rce_b[i] (scales sz=2,4) ----------------
__global__ __launch_bounds__(64) void feat_kernel(const float* __restrict__ pool,
                                                  const float* __restrict__ rce_w,
                                                  const float* __restrict__ rce_b,
                                                  float* __restrict__ feat) {
  int o = blockIdx.x, n = blockIdx.y, t = threadIdx.x;
  float part[20];
#pragma unroll
  for (int j = 0; j < 20; ++j) part[j] = 0.f;
  for (int c = t; c < 512; c += 64) {
    const float* pl = pool + ((size_t)n * 512 + c) * 20;
    float w2 = rce_w[(size_t)(128 + o) * 512 + c];
    float w4 = rce_w[(size_t)(256 + o) * 512 + c];
#pragma unroll
    for (int j = 0; j < 4; ++j)  part[j]     += w2 * pl[16 + j];
#pragma unroll
    for (int j = 0; j < 16; ++j) part[4 + j] += w4 * pl[j];
  }
  __shared__ float red[64][20];
#pragma unroll
  for (int j = 0; j < 20; ++j) red[t][j] = part[j];
  __syncthreads();
  if (t < 20) {
    float s = 0.f;
    for (int i = 0; i < 64; ++i) s += red[i][t];
    s += (t < 4) ? rce_b[128 + o] : rce_b[256 + o];
    feat[((size_t)n * 128 + o) * 20 + t] = s;
  }
}

// ------------- q/k fields, f16, layout [s][n][l][16] for MFMA attention -------------
__global__ __launch_bounds__(256) void qk2_kernel(const float* __restrict__ feat,
                                                  const float* __restrict__ q_w,
                                                  const float* __restrict__ q_b,
                                                  const float* __restrict__ k_w,
                                                  const float* __restrict__ k_b,
                                                  unsigned short* __restrict__ qh,
                                                  unsigned short* __restrict__ kh) {
  int n = blockIdx.x, t = threadIdx.x;
  __shared__ float fL[128 * 20];
  __shared__ float GH[2][16][20];
  for (int idx = t; idx < 2560; idx += 256) fL[idx] = feat[(size_t)n * 2560 + idx];
  __syncthreads();
  for (int idx = t; idx < 640; idx += 256) {
    int which = idx / 320, rem = idx % 320, qc = rem / 20, j = rem % 20;
    const float* w = which ? k_w : q_w;
    float s = which ? k_b[qc] : q_b[qc];
    for (int c = 0; c < 128; ++c) s += w[qc * 128 + c] * fL[c * 20 + j];
    GH[which][qc][j] = s;
  }
  __syncthreads();
  for (int it = 0; it < 16; ++it) {
    int row = t + 256 * it;              // 4096 rows: [s][which][l]
    int l = row & 1023, which = (row >> 10) & 1, s = row >> 11;
    int ry = l >> 5, cx = l & 31;
    int t0, t1, t2, t3;
    float w0, w1, w2, w3;
    if (s == 0) {
      float a = ry * (1.0f / 31.0f), b = cx * (1.0f / 31.0f);
      t0 = 0; t1 = 1; t2 = 2; t3 = 3;
      w0 = (1.f - a) * (1.f - b); w1 = (1.f - a) * b;
      w2 = a * (1.f - b);         w3 = a * b;
    } else {
      float pr = ry * (3.0f / 31.0f);
      int lr = (int)pr; if (lr > 2) lr = 2;
      float fr = pr - (float)lr;
      float pc = cx * (3.0f / 31.0f);
      int lc = (int)pc; if (lc > 2) lc = 2;
      float fc = pc - (float)lc;
      int base = 4 + lr * 4 + lc;
      t0 = base; t1 = base + 1; t2 = base + 4; t3 = base + 5;
      w0 = (1.f - fr) * (1.f - fc); w1 = (1.f - fr) * fc;
      w2 = fr * (1.f - fc);         w3 = fr * fc;
    }
    float val[16];
#pragma unroll
    for (int qc = 0; qc < 16; ++qc) {
      const float* G = GH[which][qc];
      val[qc] = w0 * G[t0] + w1 * G[t1] + w2 * G[t2] + w3 * G[t3];
    }
    unsigned short* dst = (which ? kh : qh) + (((size_t)(s * 16 + n) * 1024 + l) * 16);
#pragma unroll
    for (int u = 0; u < 4; ++u)
      *(ushort4*)(dst + 4 * u) = make_ushort4(f2h(val[4*u]), f2h(val[4*u+1]),
                                              f2h(val[4*u+2]), f2h(val[4*u+3]));
  }
}

// ---------------- xT[n][l][c] = f16(x[n][c][l])  (LDS tile transpose) ----------------
__global__ __launch_bounds__(256) void xcast_kernel(const float* __restrict__ x,
                                                    unsigned short* __restrict__ xT) {
  int lt = blockIdx.x, ct = blockIdx.y, n = blockIdx.z;
  int l0 = lt * 64, c0 = ct * 64, t = threadIdx.x;
  __shared__ float tile[64 * 65];
#pragma unroll
  for (int i = 0; i < 16; ++i) {
    int idx = t + 256 * i;
    int c = idx >> 6, l = idx & 63;
    tile[c * 65 + l] = x[((size_t)n * 512 + c0 + c) * 1024 + l0 + l];
  }
  __syncthreads();
#pragma unroll
  for (int i = 0; i < 16; ++i) {
    int idx = t + 256 * i;
    int l = idx >> 6, c = idx & 63;
    xT[((size_t)n * 1024 + l0 + l) * 512 + c0 + c] = f2h(tile[c * 65 + l]);
  }
}

// ---------------- vwh = f16(value_w) ----------------
__global__ __launch_bounds__(256) void vwcast_kernel(const float* __restrict__ vw,
                                                     unsigned short* __restrict__ vwh) {
  int i = blockIdx.x * 256 + threadIdx.x;
  vwh[i] = f2h(vw[i]);
}

// ------------- value-proj GEMM (f16 MFMA): pvh[c,l] = f16(sum_k vwh[c,k] xT[n][l][k] + vb) -------------
__global__ __launch_bounds__(256) void pvmm2_kernel(const unsigned short* __restrict__ vwh,
                                                    const unsigned short* __restrict__ xT,
                                                    const float* __restrict__ vb,
                                                    unsigned short* __restrict__ pvh) {
  int l0 = blockIdx.x * 64;
  int n = blockIdx.y;
  int t = threadIdx.x, lane = t & 63, wv = t >> 6;
  int wm = (wv & 1) * 64, wn = (wv >> 1) * 32;

  __shared__ short Asm[128 * 32];
  __shared__ short Bsm[64 * 32];

  int ar0 = t >> 2,        aq0 = (t & 3) ^ ((ar0 >> 1) & 3);
  int idx1 = t + 256; int ar1 = idx1 >> 2, aq1 = (idx1 & 3) ^ ((ar1 >> 1) & 3);
  int br  = t >> 2,        bq  = (t & 3) ^ ((br >> 1) & 3);
  const unsigned short* Ab0 = vwh + (size_t)ar0 * 512 + aq0 * 8;
  const unsigned short* Ab1 = vwh + (size_t)ar1 * 512 + aq1 * 8;
  const unsigned short* Bb  = xT + ((size_t)n * 1024 + l0 + br) * 512 + bq * 8;
  char* ldsA = (char*)Asm;
  char* ldsB = (char*)Bsm;
  int wvoff = wv * 1024;
  int r15 = lane & 15, kg = lane >> 4;
  int kq = kg ^ ((r15 >> 1) & 3);

  f32x4 acc[4][2];
#pragma unroll
  for (int i = 0; i < 4; ++i)
#pragma unroll
    for (int j = 0; j < 2; ++j) acc[i][j] = (f32x4){0.f, 0.f, 0.f, 0.f};

  for (int k0 = 0; k0 < 512; k0 += 32) {
    __syncthreads();
    gload_lds16(Ab0 + k0, ldsA + wvoff);
    gload_lds16(Ab1 + k0, ldsA + 4096 + wvoff);
    gload_lds16(Bb + k0,  ldsB + wvoff);
    __syncthreads();
    f16x8 af[4], bfr[2];
#pragma unroll
    for (int mt2 = 0; mt2 < 4; ++mt2)
      af[mt2] = *(const f16x8*)&Asm[(wm + mt2 * 16 + r15) * 32 + kq * 8];
#pragma unroll
    for (int nt2 = 0; nt2 < 2; ++nt2)
      bfr[nt2] = *(const f16x8*)&Bsm[(wn + nt2 * 16 + r15) * 32 + kq * 8];
#pragma unroll
    for (int mt2 = 0; mt2 < 4; ++mt2)
#pragma unroll
      for (int nt2 = 0; nt2 < 2; ++nt2)
        acc[mt2][nt2] = __builtin_amdgcn_mfma_f32_16x16x32_f16(af[mt2], bfr[nt2], acc[mt2][nt2], 0, 0, 0);
  }

  int c_lo = wm + (lane >> 4) * 4;
  int l_lo = wn + (lane & 15);
#pragma unroll
  for (int mt2 = 0; mt2 < 4; ++mt2)
#pragma unroll
    for (int nt2 = 0; nt2 < 2; ++nt2) {
      int l = l0 + l_lo + nt2 * 16;
#pragma unroll
      for (int r = 0; r < 4; ++r) {
        int c = c_lo + mt2 * 16 + r;
        pvh[((size_t)n * 128 + c) * 1024 + l] = f2h(acc[mt2][nt2][r] + vb[c]);
      }
    }
}

// ---------------- means[n][c] = mean_l pvh[n][c][l]  (sz=1 branch is constant) ----------------
__global__ __launch_bounds__(256) void mean_kernel(const unsigned short* __restrict__ pvh,
                                                   float* __restrict__ means) {
  int c = blockIdx.x, n = blockIdx.y, t = threadIdx.x;
  f16x4 v = ((const f16x4*)(pvh + ((size_t)n * 128 + c) * 1024))[t];
  float s = (float)v[0] + (float)v[1] + (float)v[2] + (float)v[3];
  for (int o = 32; o > 0; o >>= 1) s += __shfl_down(s, o);
  __shared__ float wsum[4];
  if ((t & 63) == 0) wsum[t >> 6] = s;
  __syncthreads();
  if (t == 0) means[n * 128 + c] = (wsum[0] + wsum[1] + wsum[2] + wsum[3]) * (1.f / 1024.f);
}

// ---- basecor: cor[n][oc][a*3+b] = sum over valid taps of S[ky][kx],
//      S[ky][kx] = sum_{c<128} means[n][c] * fw[oc][c][ky][kx].
//      a/b: 0 = top/left edge (ky/kx=0 cut), 1 = interior, 2 = bottom/right edge.
__global__ __launch_bounds__(64) void basecor_kernel(const float* __restrict__ means,
                                                     const float* __restrict__ fw,
                                                     float* __restrict__ cor) {
  int oc = blockIdx.x, n = blockIdx.y, t = threadIdx.x;
  float S[9];
#pragma unroll
  for (int j = 0; j < 9; ++j) S[j] = 0.f;
  for (int c = t; c < 128; c += 64) {
    float m = means[n * 128 + c];
    const float* wp = fw + (size_t)oc * 3456 + c * 9;
#pragma unroll
    for (int j = 0; j < 9; ++j) S[j] += m * wp[j];
  }
  __shared__ float red[64][9];
  __shared__ float Sf[9];
#pragma unroll
  for (int j = 0; j < 9; ++j) red[t][j] = S[j];
  __syncthreads();
  if (t < 9) {
    float s = 0.f;
    for (int i = 0; i < 64; ++i) s += red[i][t];
    Sf[t] = s;
  }
  __syncthreads();
  if (t < 9) {
    int a = t / 3, b = t % 3;
    float s = 0.f;
#pragma unroll
    for (int ky = 0; ky < 3; ++ky) {
      if ((a == 0 && ky == 0) || (a == 2 && ky == 2)) continue;
#pragma unroll
      for (int kx = 0; kx < 3; ++kx) {
        if ((b == 0 && kx == 0) || (b == 2 && kx == 2)) continue;
        s += Sf[ky * 3 + kx];
      }
    }
    cor[((size_t)n * 512 + oc) * 9 + t] = s;
  }
}

// ---- fillcat: zero the 132 border rows of each image (256 ch each) ----
__global__ __launch_bounds__(128) void fillcat_kernel(unsigned short* __restrict__ catp) {
  int b = blockIdx.x;            // n*132 + e
  int n = b / 132, e = b % 132;
  int py, px;
  if (e < 34)       { py = 0;          px = e; }
  else if (e < 68)  { py = 33;         px = e - 34; }
  else if (e < 100) { py = e - 68 + 1; px = 0; }
  else              { py = e - 100 + 1; px = 33; }
  unsigned int* row = (unsigned int*)(catp + ((size_t)n * 1156 + py * 34 + px) * 256);
  row[threadIdx.x] = 0u;         // 128 threads x 4 B = 512 B = full row
}

// ---- weight reorder+cast, FRAGMENT-MAJOR: one wave's MFMA A-fragment is a
//      contiguous 1 KB segment.  AwF chunk (mtile,g,tap,c) = 512 shorts,
//      element [r15*32 + kg*8 + i] = fw[oc=mtile*16+r15][ic=128+g*64+c*32+kg*8+i][tap]
__global__ __launch_bounds__(256) void wcast_kernel(const float* __restrict__ fw,
                                                    unsigned short* __restrict__ AwF) {
  int b = blockIdx.x, t = threadIdx.x;
  for (int j = t; j < 2304; j += 256) {
    size_t d = (size_t)b * 2304 + j;
    int off = (int)(d & 511);
    int chunk = (int)(d >> 9);
    int c = chunk & 1;
    int tapg = (chunk >> 1) % 36;
    int mtile = chunk / 72;
    int g = tapg / 9, tap = tapg % 9;
    int r15 = off >> 5, kgi = off & 31;
    int oc = mtile * 16 + r15;
    int ic = 128 + g * 64 + c * 32 + kgi;
    AwF[d] = f2bf(fw[(size_t)oc * 3456 + (size_t)ic * 9 + tap]);
  }
}

// ------------- fused flash attention (MFMA QK^T + MFMA PV, no P in HBM) -------------
__global__ __launch_bounds__(256) void fattn_kernel(const unsigned short* __restrict__ qh,
                                                    const unsigned short* __restrict__ kh,
                                                    const unsigned short* __restrict__ pvh,
                                                    unsigned short* __restrict__ catp) {
  int m0 = blockIdx.x * 64;
  int n = blockIdx.y, sc = blockIdx.z;
  int t = threadIdx.x, lane = t & 63, wv = t >> 6;
  int wc = (wv >> 1) * 64;      // c base (0/64)
  int wm2 = (wv & 1) * 32;      // m base within block tile (0/32)
  int r15 = lane & 15, kg = lane >> 4;
  int kq = kg ^ ((r15 >> 1) & 3);

  const unsigned short* qb  = qh + ((size_t)(sc * 16 + n) * 1024 + m0 + wv * 16) * 16;
  const unsigned short* kb  = kh + ((size_t)(sc * 16 + n) * 1024) * 16;
  const unsigned short* pvb = pvh + (size_t)n * 128 * 1024;

  __shared__ short PVs[2 * 128 * 32];
  __shared__ _Float16 Us[64 * 72];
  __shared__ float rsum[64];

  f16x8 zf = {0, 0, 0, 0, 0, 0, 0, 0};
  f16x8 qa = (kg < 2) ? *(const f16x8*)(qb + r15 * 16 + kg * 8) : zf;

  int prow = t >> 2;
  int aq = (t & 3) ^ ((prow >> 1) & 3);
  const unsigned short* Pb0 = pvb + (size_t)prow * 1024 + aq * 8;
  const unsigned short* Pb1 = pvb + (size_t)(prow + 64) * 1024 + aq * 8;
  char* ldsPV = (char*)PVs;
  int wvoff = wv * 1024;

  f32x4 acc[4][2];
#pragma unroll
  for (int i = 0; i < 4; ++i)
#pragma unroll
    for (int j = 0; j < 2; ++j) acc[i][j] = (f32x4){0.f, 0.f, 0.f, 0.f};
  float rs[4] = {0.f, 0.f, 0.f, 0.f};

  for (int it = 0; it < 16; ++it) {
    int l0 = it * 64;
    __syncthreads();
    gload_lds16(Pb0 + l0,      ldsPV + wvoff);
    gload_lds16(Pb1 + l0,      ldsPV + 4096 + wvoff);
    gload_lds16(Pb0 + l0 + 32, ldsPV + 8192 + wvoff);
    gload_lds16(Pb1 + l0 + 32, ldsPV + 12288 + wvoff);

    f32x4 sacc[4];
#pragma unroll
    for (int lt = 0; lt < 4; ++lt) {
      f16x8 kbf = (kg < 2)
        ? *(const f16x8*)(kb + (size_t)(l0 + lt * 16 + r15) * 16 + kg * 8) : zf;
      sacc[lt] = __builtin_amdgcn_mfma_f32_16x16x32_f16(qa, kbf, (f32x4){0.f,0.f,0.f,0.f}, 0, 0, 0);
    }
#pragma unroll
    for (int lt = 0; lt < 4; ++lt)
#pragma unroll
      for (int r = 0; r < 4; ++r) {
        float e = __expf(sacc[lt][r]);
        Us[(wv * 16 + kg * 4 + r) * 72 + lt * 16 + r15] = (_Float16)e;
        rs[r] += e;
      }
    __syncthreads();

#pragma unroll
    for (int ks = 0; ks < 2; ++ks) {
      f16x8 bfr[2];
#pragma unroll
      for (int nt = 0; nt < 2; ++nt)
        bfr[nt] = *(const f16x8*)&Us[(wm2 + nt * 16 + r15) * 72 + ks * 32 + kg * 8];
#pragma unroll
      for (int ct = 0; ct < 4; ++ct) {
        f16x8 af = *(const f16x8*)&PVs[ks * 4096 + (wc + ct * 16 + r15) * 32 + kq * 8];
#pragma unroll
        for (int nt = 0; nt < 2; ++nt)
          acc[ct][nt] = __builtin_amdgcn_mfma_f32_16x16x32_f16(af, bfr[nt], acc[ct][nt], 0, 0, 0);
      }
    }
  }

#pragma unroll
  for (int r = 0; r < 4; ++r) {
    rs[r] += __shfl_xor(rs[r], 1);
    rs[r] += __shfl_xor(rs[r], 2);
    rs[r] += __shfl_xor(rs[r], 4);
    rs[r] += __shfl_xor(rs[r], 8);
  }
  if (r15 == 0) {
#pragma unroll
    for (int r = 0; r < 4; ++r) rsum[wv * 16 + kg * 4 + r] = rs[r];
  }
  __syncthreads();

#pragma unroll
  for (int nt = 0; nt < 2; ++nt) {
    float inv = 1.f / rsum[wm2 + nt * 16 + r15];
    int pix = m0 + wm2 + nt * 16 + r15;
    unsigned short* ob = catp + ((size_t)n * 1156 + ((pix >> 5) + 1) * 34 + (pix & 31) + 1) * 256
                       + sc * 128 + wc + kg * 4;
#pragma unroll
    for (int ct = 0; ct < 4; ++ct) {
      ushort4 o = make_ushort4(f2bf(acc[ct][nt][0] * inv), f2bf(acc[ct][nt][1] * inv),
                               f2bf(acc[ct][nt][2] * inv), f2bf(acc[ct][nt][3] * inv));
      *(ushort4*)(ob + ct * 16) = o;
    }
  }
}

// ---------------- fusion conv as implicit GEMM (bf16 MFMA, K=2304) ----------------
// Barrier-free inner loop with FRAGMENT-MAJOR A: each A-fragment load is one
// coalesced 1 KB wave segment (global->VGPR, double-buffered one tap ahead);
// B halo persistent in LDS, double-buffered per 64-ic group (2 x 26 KB).
// Only 3 vmcnt(0)+s_barrier pairs per block (group boundaries) - waves
// self-pipeline: prefetch-A || ds_read-B || MFMA.
// mean-channel contribution added from cor[n][oc][3x3] in the epilogue.
__global__ __launch_bounds__(256) void convmm_kernel(const unsigned short* __restrict__ AwF,
                                                     const unsigned short* __restrict__ catp,
                                                     const float* __restrict__ cor,
                                                     float* __restrict__ y) {
  int ntile = blockIdx.x;
  int n = ntile >> 3, y0 = (ntile & 7) * 4;
  int m0 = blockIdx.y * 128;
  int t = threadIdx.x;
  int lane = t & 63, wv = t >> 6;
  int wm = (wv & 1) * 64, wn = (wv >> 1) * 64;

  __shared__ short Bimg[2 * 208 * 64];      // [buf][208 px][64 ic], chunk-swizzled, 52 KB
  char* ldsB = (char*)Bimg;

  // ---- B halo staging: lane covers (px = j*8 + lane/8, chunk = lane%8); source
  // chunk pre-swizzled by px so tap-shifted reads land conflict-free ----
  const unsigned short* cb = catp + ((size_t)n * 1156 + (size_t)y0 * 34) * 256;
  int bpx = lane >> 3;
  int bch = (lane & 7) ^ (bpx & 7);

  int r15 = lane & 15, kg = lane >> 4;

  // fragment-major A base: chunk(mtile,g,tap,c) = 512 shorts; lane elem r15*32+kg*8.
  // strides (shorts): c +512, tap +1024, g +9216, mtile +36864.
  int mtilebase = blockIdx.y * 8 + (wv & 1) * 4;
  const unsigned short* Ap = AwF + (size_t)mtilebase * 36864 + r15 * 32 + kg * 8;

  // per-nt pixel base within the halo strip (row r -> +34, col x -> +1)
  int pxl[4];
#pragma unroll
  for (int nt = 0; nt < 4; ++nt) {
    int pn = wn + nt * 16 + r15;
    pxl[nt] = (pn >> 5) * 34 + (pn & 31);
  }

  f32x4 acc[4][4];
#pragma unroll
  for (int i = 0; i < 4; ++i)
#pragma unroll
    for (int j = 0; j < 4; ++j) acc[i][j] = (f32x4){0.f, 0.f, 0.f, 0.f};

  bf16x8 Ar[2][8];   // double-buffered A fragments (parity = (g + tap) & 1)

  // prologue: stage B(g=0) -> buf0; prefetch A(g=0,tap=0) -> Ar[0]
  for (int j = wv; j < 26; j += 4)
    gload_lds16(cb + (size_t)(j * 8 + bpx) * 256 + bch * 8, ldsB + j * 1024);
#pragma unroll
  for (int c = 0; c < 2; ++c)
#pragma unroll
    for (int mt = 0; mt < 4; ++mt)
      Ar[0][c * 4 + mt] = *(const bf16x8*)(Ap + (size_t)mt * 36864 + c * 512);
  asm volatile("s_waitcnt vmcnt(0)" ::: "memory");
  __builtin_amdgcn_s_barrier();

#pragma unroll 2
  for (int g = 0; g < 4; ++g) {
    int gpar = g & 1;
    // stage next group's B halo early (overlaps with this group's 9 taps)
    if (g < 3) {
      for (int j = wv; j < 26; j += 4)
        gload_lds16(cb + (size_t)(j * 8 + bpx) * 256 + (g + 1) * 64 + bch * 8,
                    ldsB + (gpar ^ 1) * 26624 + j * 1024);
    }
    const unsigned short* Agbase = Ap + (size_t)g * 9216;
#pragma unroll
    for (int tap = 0; tap < 9; ++tap) {
      int par = (g + tap) & 1;     // static: g unrolled x2, tap fully unrolled
      // prefetch next tap's A fragments (one coalesced 1 KB load each)
      if (!(g == 3 && tap == 8)) {
        const unsigned short* An = (tap == 8) ? (Agbase + 9216) : (Agbase + (tap + 1) * 1024);
#pragma unroll
        for (int c = 0; c < 2; ++c)
#pragma unroll
          for (int mt = 0; mt < 4; ++mt)
            Ar[par ^ 1][c * 4 + mt] = *(const bf16x8*)(An + (size_t)mt * 36864 + c * 512);
      }
      int sy = tap / 3;
      int toff = sy * 34 + (tap - sy * 3);
      bf16x8 bfv[2][4];
#pragma unroll
      for (int c = 0; c < 2; ++c)
#pragma unroll
        for (int nt = 0; nt < 4; ++nt) {
          int px = pxl[nt] + toff;
          int lch = (c * 4 + kg) ^ (px & 7);
          bfv[c][nt] = *(const bf16x8*)&Bimg[gpar * 13312 + px * 64 + lch * 8];
        }
#pragma unroll
      for (int c = 0; c < 2; ++c)
#pragma unroll
        for (int mt = 0; mt < 4; ++mt)
#pragma unroll
          for (int nt = 0; nt < 4; ++nt)
            acc[mt][nt] = __builtin_amdgcn_mfma_f32_16x16x32_bf16(
                Ar[par][c * 4 + mt], bfv[c][nt], acc[mt][nt], 0, 0, 0);
    }
    if (g < 3) {
      // own B(g+1)/A loads drained, then all waves' LDS writes visible
      asm volatile("s_waitcnt vmcnt(0)" ::: "memory");
      __builtin_amdgcn_s_barrier();
    }
  }

  int pixbase = (ntile & 7) * 128 + wn + (lane & 15);
  int ocbase = m0 + wm + (lane >> 4) * 4;
#pragma unroll
  for (int mt = 0; mt < 4; ++mt)
#pragma unroll
    for (int nt = 0; nt < 4; ++nt) {
      int oc = ocbase + mt * 16;
      int pix = pixbase + nt * 16;
      int py = pix >> 5, px = pix & 31;
      int yc = (py == 0) ? 0 : ((py == 31) ? 2 : 1);
      int xc = (px == 0) ? 0 : ((px == 31) ? 2 : 1);
      const float* cp = cor + ((size_t)n * 512 + oc) * 9 + yc * 3 + xc;
      float* yp = y + ((size_t)n * 512 + oc) * 1024 + pix;
#pragma unroll
      for (int r = 0; r < 4; ++r) yp[(size_t)r * 1024] = acc[mt][nt][r] + cp[(size_t)r * 9];
    }
}

// ---------------- BN batch stats per channel ----------------
__global__ __launch_bounds__(256) void bnstat_kernel(const float* __restrict__ y,
                                                     const float* __restrict__ bn_scale,
                                                     const float* __restrict__ bn_bias,
                                                     float* __restrict__ stats) {
  int oc = blockIdx.x, t = threadIdx.x;
  float s = 0.f, ss = 0.f;
  for (int n = 0; n < 16; ++n) {
    float4 v = ((const float4*)(y + ((size_t)n * 512 + oc) * 1024))[t];
    s  += v.x + v.y + v.z + v.w;
    ss += v.x * v.x + v.y * v.y + v.z * v.z + v.w * v.w;
  }
  for (int o = 32; o > 0; o >>= 1) {
    s  += __shfl_down(s, o);
    ss += __shfl_down(ss, o);
  }
  __shared__ float rs[4], rss[4];
  if ((t & 63) == 0) { rs[t >> 6] = s; rss[t >> 6] = ss; }
  __syncthreads();
  if (t == 0) {
    float S = rs[0] + rs[1] + rs[2] + rs[3];
    float SS = rss[0] + rss[1] + rss[2] + rss[3];
    float mean = S * (1.f / 16384.f);
    float var = SS * (1.f / 16384.f) - mean * mean;
    float se = bn_scale[oc] / sqrtf(var + 1e-5f);
    stats[oc * 2] = se;
    stats[oc * 2 + 1] = bn_bias[oc] - mean * se;
  }
}

// ---------------- normalize + relu + gamma*y + x ----------------
__global__ __launch_bounds__(256) void final_kernel(const float* __restrict__ y,
                                                    const float* __restrict__ x,
                                                    const float* __restrict__ stats,
                                                    const float* __restrict__ gamma,
                                                    float* __restrict__ outp) {
  int b = blockIdx.x;
  int c = b & 511;
  int t = threadIdx.x;
  float se = stats[c * 2], sh = stats[c * 2 + 1], g = gamma[0];
  float4 yv = ((const float4*)(y + (size_t)b * 1024))[t];
  float4 xv = ((const float4*)(x + (size_t)b * 1024))[t];
  float4 o;
  o.x = g * fmaxf(yv.x * se + sh, 0.f) + xv.x;
  o.y = g * fmaxf(yv.y * se + sh, 0.f) + xv.y;
  o.z = g * fmaxf(yv.z * se + sh, 0.f) + xv.z;
  o.w = g * fmaxf(yv.w * se + sh, 0.f) + xv.w;
  ((float4*)(outp + (size_t)b * 1024))[t] = o;
}

extern "C" void kernel_launch(void* const* d_in, const int* in_sizes, int n_in,
                              void* d_out, int out_size, void* d_ws, size_t ws_size,
                              hipStream_t stream) {
  const float* x        = (const float*)d_in[0];
  const float* rce_w    = (const float*)d_in[1];
  const float* rce_b    = (const float*)d_in[2];
  const float* q_w      = (const float*)d_in[3];
  const float* q_b      = (const float*)d_in[4];
  const float* k_w      = (const float*)d_in[5];
  const float* k_b      = (const float*)d_in[6];
  const float* value_w  = (const float*)d_in[7];
  const float* value_b  = (const float*)d_in[8];
  const float* fw       = (const float*)d_in[9];
  const float* bn_scale = (const float*)d_in[10];
  const float* bn_bias  = (const float*)d_in[11];
  const float* gamma    = (const float*)d_in[12];

  float* ws    = (float*)d_ws;
  float* cor   = ws + OFF_COR;
  unsigned short* pvh = (unsigned short*)(ws + OFF_PVH);
  float* ybuf  = ws + OFF_Y;
  unsigned short* xTbuf = (unsigned short*)(ws + OFF_Y);  // union: dead before convmm
  unsigned short* catp = (unsigned short*)(ws + OFF_CATP);
  unsigned short* qh   = (unsigned short*)(ws + OFF_QH);
  unsigned short* kh   = (unsigned short*)(ws + OFF_KH);
  float* pool  = ws + OFF_POOL;
  float* feat  = ws + OFF_FEAT;
  unsigned short* Aw = (unsigned short*)(ws + OFF_AW);
  float* means = ws + OFF_MEANS;
  float* stats = ws + OFF_STAT;
  unsigned short* vwh = (unsigned short*)(ws + OFF_VWH);
  float* outp  = (float*)d_out;

  hipLaunchKernelGGL(pool_kernel,    dim3(8192),       dim3(256), 0, stream, x, pool);
  hipLaunchKernelGGL(feat_kernel,    dim3(128, 16),    dim3(64),  0, stream, pool, rce_w, rce_b, feat);
  hipLaunchKernelGGL(qk2_kernel,     dim3(16),         dim3(256), 0, stream, feat, q_w, q_b, k_w, k_b, qh, kh);
  hipLaunchKernelGGL(xcast_kernel,   dim3(16, 8, 16),  dim3(256), 0, stream, x, xTbuf);
  hipLaunchKernelGGL(vwcast_kernel,  dim3(256),        dim3(256), 0, stream, value_w, vwh);
  hipLaunchKernelGGL(pvmm2_kernel,   dim3(16, 16),     dim3(256), 0, stream, vwh, xTbuf, value_b, pvh);
  hipLaunchKernelGGL(mean_kernel,    dim3(128, 16),    dim3(256), 0, stream, pvh, means);
  hipLaunchKernelGGL(basecor_kernel, dim3(512, 16),    dim3(64),  0, stream, means, fw, cor);
  hipLaunchKernelGGL(fillcat_kernel, dim3(2112),       dim3(128), 0, stream, catp);
  hipLaunchKernelGGL(wcast_kernel,   dim3(512),        dim3(256), 0, stream, fw, Aw);
  hipLaunchKernelGGL(fattn_kernel,   dim3(16, 16, 2),  dim3(256), 0, stream, qh, kh, pvh, catp);
  hipLaunchKernelGGL(convmm_kernel,  dim3(128, 4),     dim3(256), 0, stream, Aw, catp, cor, ybuf);
  hipLaunchKernelGGL(bnstat_kernel,  dim3(512),        dim3(256), 0, stream, ybuf, bn_scale, bn_bias, stats);
  hipLaunchKernelGGL(final_kernel,   dim3(8192),       dim3(256), 0, stream, ybuf, x, stats, gamma, outp);
}

// Round 6
// 277.602 us; speedup vs baseline: 1.1449x; 1.1062x over previous
//
#include <hip/hip_runtime.h>
#include <hip/hip_fp16.h>
#include <math.h>

// n=16, C=512, c4=128, qk=16, H=W=32, L=1024. fp32 in/out.
// conv (K=2304, mean-channels factored out analytically) + fused flash attention
// + value-proj, all matmuls on MFMA.
//
// ws layout (float offsets):
#define OFF_COR   0u          // cor   [16][512][9] f32 (mean-channel conv contribution)
#define OFF_PVH   2097152u    // pvh   [16][128][1024] f16
#define OFF_Y     3145728u    // y     [16][512][1024] f32
                              //   UNION: xT f16 [16][1024][512] (dead before convmm)
#define OFF_CATP  11534336u   // catT_p[16][1156][256] bf16 (pixel-major, 34x34 zero-padded)
#define OFF_QH    15085568u   // qh    [2][16][1024][16] f16
#define OFF_KH    15347712u   // kh    [2][16][1024][16] f16
#define OFF_POOL  16134144u   // pool  [16][512][20] f32
#define OFF_FEAT  16297984u   // feat  [16][128][20] f32
#define OFF_AW    16338944u   // Aw    [512][2304] bf16 (k = (ky*3+kx)*256 + (ic-128))
#define OFF_MEANS 17223680u   // means [16][128] f32
#define OFF_STAT  17225728u   // stats [512][2] f32
#define OFF_VWH   17226752u   // vwh   [128][512] f16

typedef __bf16 bf16x8 __attribute__((ext_vector_type(8)));
typedef _Float16 f16x8 __attribute__((ext_vector_type(8)));
typedef _Float16 f16x4 __attribute__((ext_vector_type(4)));
typedef float f32x4 __attribute__((ext_vector_type(4)));

__device__ __forceinline__ unsigned short f2bf(float f) {
  unsigned int u = __float_as_uint(f);
  unsigned int r = u + 0x7fff + ((u >> 16) & 1);   // RNE
  return (unsigned short)(r >> 16);
}

__device__ __forceinline__ unsigned short f2h(float f) {
  union { _Float16 h; unsigned short u; } cv;
  cv.h = (_Float16)f;
  return cv.u;
}

__device__ __forceinline__ void gload_lds16(const void* g, void* l) {
  __builtin_amdgcn_global_load_lds(
      (const __attribute__((address_space(1))) unsigned int*)g,
      (__attribute__((address_space(3))) unsigned int*)l, 16, 0, 0);
}

// ---------------- pooling: pooled4 (8x8 blocks) + pooled2 derived ----------------
__global__ __launch_bounds__(256) void pool_kernel(const float* __restrict__ x,
                                                   float* __restrict__ pool) {
  int b = blockIdx.x;            // n*512 + c
  int t = threadIdx.x;
  const float4* xp = (const float4*)(x + (size_t)b * 1024);
  float4 v = xp[t];
  float s4 = v.x + v.y + v.z + v.w;
  __shared__ float sm[256];
  __shared__ float p4s[16];
  sm[t] = s4;
  __syncthreads();
  if (t < 16) {
    int br = t >> 2, bc = t & 3;
    float s = 0.f;
#pragma unroll
    for (int rr = 0; rr < 8; ++rr) {
      int base = br * 64 + rr * 8 + bc * 2;
      s += sm[base] + sm[base + 1];
    }
    s *= (1.f / 64.f);
    p4s[t] = s;
    pool[(size_t)b * 20 + t] = s;
  }
  __syncthreads();
  if (t < 4) {
    int i2 = t >> 1, j2 = t & 1;
    float s = (p4s[(2*i2)*4 + 2*j2]     + p4s[(2*i2)*4 + 2*j2 + 1] +
               p4s[(2*i2+1)*4 + 2*j2]   + p4s[(2*i2+1)*4 + 2*j2 + 1]) * 0.25f;
    pool[(size_t)b * 20 + 16 + t] = s;
  }
}

// ---------------- feat = rce_w[i] @ pooled_i + rce_b[i] (scales sz=2,4) ----------------
__global__ __launch_bounds__(64) void feat_kernel(const float* __restrict__ pool,
                                                  const float* __restrict__ rce_w,
                                                  const float* __restrict__ rce_b,
                                                  float* __restrict__ feat) {
  int o = blockIdx.x, n = blockIdx.y, t = threadIdx.x;
  float part[20];
#pragma unroll
  for (int j = 0; j < 20; ++j) part[j] = 0.f;
  for (int c = t; c < 512; c += 64) {
    const float* pl = pool + ((size_t)n * 512 + c) * 20;
    float w2 = rce_w[(size_t)(128 + o) * 512 + c];
    float w4 = rce_w[(size_t)(256 + o) * 512 + c];
#pragma unroll
    for (int j = 0; j < 4; ++j)  part[j]     += w2 * pl[16 + j];
#pragma unroll
    for (int j = 0; j < 16; ++j) part[4 + j] += w4 * pl[j];
  }
  __shared__ float red[64][20];
#pragma unroll
  for (int j = 0; j < 20; ++j) red[t][j] = part[j];
  __syncthreads();
  if (t < 20) {
    float s = 0.f;
    for (int i = 0; i < 64; ++i) s += red[i][t];
    s += (t < 4) ? rce_b[128 + o] : rce_b[256 + o];
    feat[((size_t)n * 128 + o) * 20 + t] = s;
  }
}

// ------------- q/k fields, f16, layout [s][n][l][16] for MFMA attention -------------
__global__ __launch_bounds__(256) void qk2_kernel(const float* __restrict__ feat,
                                                  const float* __restrict__ q_w,
                                                  const float* __restrict__ q_b,
                                                  const float* __restrict__ k_w,
                                                  const float* __restrict__ k_b,
                                                  unsigned short* __restrict__ qh,
                                                  unsigned short* __restrict__ kh) {
  int n = blockIdx.x, t = threadIdx.x;
  __shared__ float fL[128 * 20];
  __shared__ float GH[2][16][20];
  for (int idx = t; idx < 2560; idx += 256) fL[idx] = feat[(size_t)n * 2560 + idx];
  __syncthreads();
  for (int idx = t; idx < 640; idx += 256) {
    int which = idx / 320, rem = idx % 320, qc = rem / 20, j = rem % 20;
    const float* w = which ? k_w : q_w;
    float s = which ? k_b[qc] : q_b[qc];
    for (int c = 0; c < 128; ++c) s += w[qc * 128 + c] * fL[c * 20 + j];
    GH[which][qc][j] = s;
  }
  __syncthreads();
  for (int it = 0; it < 16; ++it) {
    int row = t + 256 * it;              // 4096 rows: [s][which][l]
    int l = row & 1023, which = (row >> 10) & 1, s = row >> 11;
    int ry = l >> 5, cx = l & 31;
    int t0, t1, t2, t3;
    float w0, w1, w2, w3;
    if (s == 0) {
      float a = ry * (1.0f / 31.0f), b = cx * (1.0f / 31.0f);
      t0 = 0; t1 = 1; t2 = 2; t3 = 3;
      w0 = (1.f - a) * (1.f - b); w1 = (1.f - a) * b;
      w2 = a * (1.f - b);         w3 = a * b;
    } else {
      float pr = ry * (3.0f / 31.0f);
      int lr = (int)pr; if (lr > 2) lr = 2;
      float fr = pr - (float)lr;
      float pc = cx * (3.0f / 31.0f);
      int lc = (int)pc; if (lc > 2) lc = 2;
      float fc = pc - (float)lc;
      int base = 4 + lr * 4 + lc;
      t0 = base; t1 = base + 1; t2 = base + 4; t3 = base + 5;
      w0 = (1.f - fr) * (1.f - fc); w1 = (1.f - fr) * fc;
      w2 = fr * (1.f - fc);         w3 = fr * fc;
    }
    float val[16];
#pragma unroll
    for (int qc = 0; qc < 16; ++qc) {
      const float* G = GH[which][qc];
      val[qc] = w0 * G[t0] + w1 * G[t1] + w2 * G[t2] + w3 * G[t3];
    }
    unsigned short* dst = (which ? kh : qh) + (((size_t)(s * 16 + n) * 1024 + l) * 16);
#pragma unroll
    for (int u = 0; u < 4; ++u)
      *(ushort4*)(dst + 4 * u) = make_ushort4(f2h(val[4*u]), f2h(val[4*u+1]),
                                              f2h(val[4*u+2]), f2h(val[4*u+3]));
  }
}

// ---------------- xT[n][l][c] = f16(x[n][c][l])  (LDS tile transpose) ----------------
__global__ __launch_bounds__(256) void xcast_kernel(const float* __restrict__ x,
                                                    unsigned short* __restrict__ xT) {
  int lt = blockIdx.x, ct = blockIdx.y, n = blockIdx.z;
  int l0 = lt * 64, c0 = ct * 64, t = threadIdx.x;
  __shared__ float tile[64 * 65];
#pragma unroll
  for (int i = 0; i < 16; ++i) {
    int idx = t + 256 * i;
    int c = idx >> 6, l = idx & 63;
    tile[c * 65 + l] = x[((size_t)n * 512 + c0 + c) * 1024 + l0 + l];
  }
  __syncthreads();
#pragma unroll
  for (int i = 0; i < 16; ++i) {
    int idx = t + 256 * i;
    int l = idx >> 6, c = idx & 63;
    xT[((size_t)n * 1024 + l0 + l) * 512 + c0 + c] = f2h(tile[c * 65 + l]);
  }
}

// ---------------- vwh = f16(value_w) ----------------
__global__ __launch_bounds__(256) void vwcast_kernel(const float* __restrict__ vw,
                                                     unsigned short* __restrict__ vwh) {
  int i = blockIdx.x * 256 + threadIdx.x;
  vwh[i] = f2h(vw[i]);
}

// ------------- value-proj GEMM (f16 MFMA): pvh[c,l] = f16(sum_k vwh[c,k] xT[n][l][k] + vb) -------------
__global__ __launch_bounds__(256) void pvmm2_kernel(const unsigned short* __restrict__ vwh,
                                                    const unsigned short* __restrict__ xT,
                                                    const float* __restrict__ vb,
                                                    unsigned short* __restrict__ pvh) {
  int l0 = blockIdx.x * 64;
  int n = blockIdx.y;
  int t = threadIdx.x, lane = t & 63, wv = t >> 6;
  int wm = (wv & 1) * 64, wn = (wv >> 1) * 32;

  __shared__ short Asm[128 * 32];
  __shared__ short Bsm[64 * 32];

  int ar0 = t >> 2,        aq0 = (t & 3) ^ ((ar0 >> 1) & 3);
  int idx1 = t + 256; int ar1 = idx1 >> 2, aq1 = (idx1 & 3) ^ ((ar1 >> 1) & 3);
  int br  = t >> 2,        bq  = (t & 3) ^ ((br >> 1) & 3);
  const unsigned short* Ab0 = vwh + (size_t)ar0 * 512 + aq0 * 8;
  const unsigned short* Ab1 = vwh + (size_t)ar1 * 512 + aq1 * 8;
  const unsigned short* Bb  = xT + ((size_t)n * 1024 + l0 + br) * 512 + bq * 8;
  char* ldsA = (char*)Asm;
  char* ldsB = (char*)Bsm;
  int wvoff = wv * 1024;
  int r15 = lane & 15, kg = lane >> 4;
  int kq = kg ^ ((r15 >> 1) & 3);

  f32x4 acc[4][2];
#pragma unroll
  for (int i = 0; i < 4; ++i)
#pragma unroll
    for (int j = 0; j < 2; ++j) acc[i][j] = (f32x4){0.f, 0.f, 0.f, 0.f};

  for (int k0 = 0; k0 < 512; k0 += 32) {
    __syncthreads();
    gload_lds16(Ab0 + k0, ldsA + wvoff);
    gload_lds16(Ab1 + k0, ldsA + 4096 + wvoff);
    gload_lds16(Bb + k0,  ldsB + wvoff);
    __syncthreads();
    f16x8 af[4], bfr[2];
#pragma unroll
    for (int mt2 = 0; mt2 < 4; ++mt2)
      af[mt2] = *(const f16x8*)&Asm[(wm + mt2 * 16 + r15) * 32 + kq * 8];
#pragma unroll
    for (int nt2 = 0; nt2 < 2; ++nt2)
      bfr[nt2] = *(const f16x8*)&Bsm[(wn + nt2 * 16 + r15) * 32 + kq * 8];
#pragma unroll
    for (int mt2 = 0; mt2 < 4; ++mt2)
#pragma unroll
      for (int nt2 = 0; nt2 < 2; ++nt2)
        acc[mt2][nt2] = __builtin_amdgcn_mfma_f32_16x16x32_f16(af[mt2], bfr[nt2], acc[mt2][nt2], 0, 0, 0);
  }

  int c_lo = wm + (lane >> 4) * 4;
  int l_lo = wn + (lane & 15);
#pragma unroll
  for (int mt2 = 0; mt2 < 4; ++mt2)
#pragma unroll
    for (int nt2 = 0; nt2 < 2; ++nt2) {
      int l = l0 + l_lo + nt2 * 16;
#pragma unroll
      for (int r = 0; r < 4; ++r) {
        int c = c_lo + mt2 * 16 + r;
        pvh[((size_t)n * 128 + c) * 1024 + l] = f2h(acc[mt2][nt2][r] + vb[c]);
      }
    }
}

// ---------------- means[n][c] = mean_l pvh[n][c][l]  (sz=1 branch is constant) ----------------
__global__ __launch_bounds__(256) void mean_kernel(const unsigned short* __restrict__ pvh,
                                                   float* __restrict__ means) {
  int c = blockIdx.x, n = blockIdx.y, t = threadIdx.x;
  f16x4 v = ((const f16x4*)(pvh + ((size_t)n * 128 + c) * 1024))[t];
  float s = (float)v[0] + (float)v[1] + (float)v[2] + (float)v[3];
  for (int o = 32; o > 0; o >>= 1) s += __shfl_down(s, o);
  __shared__ float wsum[4];
  if ((t & 63) == 0) wsum[t >> 6] = s;
  __syncthreads();
  if (t == 0) means[n * 128 + c] = (wsum[0] + wsum[1] + wsum[2] + wsum[3]) * (1.f / 1024.f);
}

// ---- basecor: cor[n][oc][a*3+b] = sum over valid taps of S[ky][kx],
//      S[ky][kx] = sum_{c<128} means[n][c] * fw[oc][c][ky][kx].
//      a/b: 0 = top/left edge (ky/kx=0 cut), 1 = interior, 2 = bottom/right edge.
__global__ __launch_bounds__(64) void basecor_kernel(const float* __restrict__ means,
                                                     const float* __restrict__ fw,
                                                     float* __restrict__ cor) {
  int oc = blockIdx.x, n = blockIdx.y, t = threadIdx.x;
  float S[9];
#pragma unroll
  for (int j = 0; j < 9; ++j) S[j] = 0.f;
  for (int c = t; c < 128; c += 64) {
    float m = means[n * 128 + c];
    const float* wp = fw + (size_t)oc * 3456 + c * 9;
#pragma unroll
    for (int j = 0; j < 9; ++j) S[j] += m * wp[j];
  }
  __shared__ float red[64][9];
  __shared__ float Sf[9];
#pragma unroll
  for (int j = 0; j < 9; ++j) red[t][j] = S[j];
  __syncthreads();
  if (t < 9) {
    float s = 0.f;
    for (int i = 0; i < 64; ++i) s += red[i][t];
    Sf[t] = s;
  }
  __syncthreads();
  if (t < 9) {
    int a = t / 3, b = t % 3;
    float s = 0.f;
#pragma unroll
    for (int ky = 0; ky < 3; ++ky) {
      if ((a == 0 && ky == 0) || (a == 2 && ky == 2)) continue;
#pragma unroll
      for (int kx = 0; kx < 3; ++kx) {
        if ((b == 0 && kx == 0) || (b == 2 && kx == 2)) continue;
        s += Sf[ky * 3 + kx];
      }
    }
    cor[((size_t)n * 512 + oc) * 9 + t] = s;
  }
}

// ---- fillcat: zero the 132 border rows of each image (256 ch each) ----
__global__ __launch_bounds__(128) void fillcat_kernel(unsigned short* __restrict__ catp) {
  int b = blockIdx.x;            // n*132 + e
  int n = b / 132, e = b % 132;
  int py, px;
  if (e < 34)       { py = 0;          px = e; }
  else if (e < 68)  { py = 33;         px = e - 34; }
  else if (e < 100) { py = e - 68 + 1; px = 0; }
  else              { py = e - 100 + 1; px = 33; }
  unsigned int* row = (unsigned int*)(catp + ((size_t)n * 1156 + py * 34 + px) * 256);
  row[threadIdx.x] = 0u;         // 128 threads x 4 B = 512 B = full row
}

// ---------------- weight reorder+cast: Aw[oc][seg*256 + (ic-128)] ----------------
__global__ __launch_bounds__(256) void wcast_kernel(const float* __restrict__ fw,
                                                    unsigned short* __restrict__ Aw) {
  int oc = blockIdx.x, t = threadIdx.x;
  for (int j = t; j < 2304; j += 256) {
    int seg = j >> 8, ic2 = j & 255;
    Aw[(size_t)oc * 2304 + j] = f2bf(fw[(size_t)oc * 3456 + (128 + ic2) * 9 + seg]);
  }
}

// ------------- fused flash attention (MFMA QK^T + MFMA PV, no P in HBM) -------------
__global__ __launch_bounds__(256) void fattn_kernel(const unsigned short* __restrict__ qh,
                                                    const unsigned short* __restrict__ kh,
                                                    const unsigned short* __restrict__ pvh,
                                                    unsigned short* __restrict__ catp) {
  int m0 = blockIdx.x * 64;
  int n = blockIdx.y, sc = blockIdx.z;
  int t = threadIdx.x, lane = t & 63, wv = t >> 6;
  int wc = (wv >> 1) * 64;      // c base (0/64)
  int wm2 = (wv & 1) * 32;      // m base within block tile (0/32)
  int r15 = lane & 15, kg = lane >> 4;
  int kq = kg ^ ((r15 >> 1) & 3);

  const unsigned short* qb  = qh + ((size_t)(sc * 16 + n) * 1024 + m0 + wv * 16) * 16;
  const unsigned short* kb  = kh + ((size_t)(sc * 16 + n) * 1024) * 16;
  const unsigned short* pvb = pvh + (size_t)n * 128 * 1024;

  __shared__ short PVs[2 * 128 * 32];
  __shared__ _Float16 Us[64 * 72];
  __shared__ float rsum[64];

  f16x8 zf = {0, 0, 0, 0, 0, 0, 0, 0};
  f16x8 qa = (kg < 2) ? *(const f16x8*)(qb + r15 * 16 + kg * 8) : zf;

  int prow = t >> 2;
  int aq = (t & 3) ^ ((prow >> 1) & 3);
  const unsigned short* Pb0 = pvb + (size_t)prow * 1024 + aq * 8;
  const unsigned short* Pb1 = pvb + (size_t)(prow + 64) * 1024 + aq * 8;
  char* ldsPV = (char*)PVs;
  int wvoff = wv * 1024;

  f32x4 acc[4][2];
#pragma unroll
  for (int i = 0; i < 4; ++i)
#pragma unroll
    for (int j = 0; j < 2; ++j) acc[i][j] = (f32x4){0.f, 0.f, 0.f, 0.f};
  float rs[4] = {0.f, 0.f, 0.f, 0.f};

  for (int it = 0; it < 16; ++it) {
    int l0 = it * 64;
    __syncthreads();
    gload_lds16(Pb0 + l0,      ldsPV + wvoff);
    gload_lds16(Pb1 + l0,      ldsPV + 4096 + wvoff);
    gload_lds16(Pb0 + l0 + 32, ldsPV + 8192 + wvoff);
    gload_lds16(Pb1 + l0 + 32, ldsPV + 12288 + wvoff);

    f32x4 sacc[4];
#pragma unroll
    for (int lt = 0; lt < 4; ++lt) {
      f16x8 kbf = (kg < 2)
        ? *(const f16x8*)(kb + (size_t)(l0 + lt * 16 + r15) * 16 + kg * 8) : zf;
      sacc[lt] = __builtin_amdgcn_mfma_f32_16x16x32_f16(qa, kbf, (f32x4){0.f,0.f,0.f,0.f}, 0, 0, 0);
    }
#pragma unroll
    for (int lt = 0; lt < 4; ++lt)
#pragma unroll
      for (int r = 0; r < 4; ++r) {
        float e = __expf(sacc[lt][r]);
        Us[(wv * 16 + kg * 4 + r) * 72 + lt * 16 + r15] = (_Float16)e;
        rs[r] += e;
      }
    __syncthreads();

#pragma unroll
    for (int ks = 0; ks < 2; ++ks) {
      f16x8 bfr[2];
#pragma unroll
      for (int nt = 0; nt < 2; ++nt)
        bfr[nt] = *(const f16x8*)&Us[(wm2 + nt * 16 + r15) * 72 + ks * 32 + kg * 8];
#pragma unroll
      for (int ct = 0; ct < 4; ++ct) {
        f16x8 af = *(const f16x8*)&PVs[ks * 4096 + (wc + ct * 16 + r15) * 32 + kq * 8];
#pragma unroll
        for (int nt = 0; nt < 2; ++nt)
          acc[ct][nt] = __builtin_amdgcn_mfma_f32_16x16x32_f16(af, bfr[nt], acc[ct][nt], 0, 0, 0);
      }
    }
  }

#pragma unroll
  for (int r = 0; r < 4; ++r) {
    rs[r] += __shfl_xor(rs[r], 1);
    rs[r] += __shfl_xor(rs[r], 2);
    rs[r] += __shfl_xor(rs[r], 4);
    rs[r] += __shfl_xor(rs[r], 8);
  }
  if (r15 == 0) {
#pragma unroll
    for (int r = 0; r < 4; ++r) rsum[wv * 16 + kg * 4 + r] = rs[r];
  }
  __syncthreads();

#pragma unroll
  for (int nt = 0; nt < 2; ++nt) {
    float inv = 1.f / rsum[wm2 + nt * 16 + r15];
    int pix = m0 + wm2 + nt * 16 + r15;
    unsigned short* ob = catp + ((size_t)n * 1156 + ((pix >> 5) + 1) * 34 + (pix & 31) + 1) * 256
                       + sc * 128 + wc + kg * 4;
#pragma unroll
    for (int ct = 0; ct < 4; ++ct) {
      ushort4 o = make_ushort4(f2bf(acc[ct][nt][0] * inv), f2bf(acc[ct][nt][1] * inv),
                               f2bf(acc[ct][nt][2] * inv), f2bf(acc[ct][nt][3] * inv));
      *(ushort4*)(ob + ct * 16) = o;
    }
  }
}

// ---------------- fusion conv as implicit GEMM (bf16 MFMA, K=2304) ----------------
// R1-proven 2-phase schedule (stage s+1 before compute s, one __syncthreads per
// BK=64 tile), but with BM=64 x BN=128 tiles: grid doubles to 1024 blocks and
// LDS drops to 48 KB -> 3 blocks/CU resident (12 waves/CU, was 8). Occupancy
// was grid-limited at the 128x128 tile; this lifts the latency-hiding cap.
// mean-channel contribution added from cor[n][oc][3x3] in the epilogue.
__device__ __forceinline__ void conv_stage(const unsigned short* __restrict__ Aw,
                                           const unsigned short* __restrict__ catp,
                                           size_t abase0,
                                           size_t bbase0, size_t bbase1,
                                           int s, char* la, char* lb, int wvoff) {
  int seg = s >> 2;                                  // k = s*64 .. s*64+63, all in one seg
  size_t akk  = (size_t)s * 64;
  size_t boff = (size_t)((seg / 3) * 34 + (seg % 3)) * 256 + (size_t)(s & 3) * 64;
  gload_lds16(Aw + abase0 + akk,          la + wvoff);            // A rows 0-63, k chunk 0
  gload_lds16(Aw + abase0 + akk + 32,     la + 4096 + wvoff);     // A rows 0-63, k chunk 1
  gload_lds16(catp + bbase0 + boff,       lb + wvoff);            // B px 0-63,  chunk 0
  gload_lds16(catp + bbase1 + boff,       lb + 4096 + wvoff);     // B px 64-127, chunk 0
  gload_lds16(catp + bbase0 + boff + 32,  lb + 8192 + wvoff);     // B px 0-63,  chunk 1
  gload_lds16(catp + bbase1 + boff + 32,  lb + 12288 + wvoff);    // B px 64-127, chunk 1
}

__device__ __forceinline__ void conv_comp(const short* As_, const short* Bs_,
                                          int wm, int wn, int r15, int kq,
                                          f32x4 acc[2][4]) {
  bf16x8 af[2], bfv[4];
#pragma unroll
  for (int mt = 0; mt < 2; ++mt)
    af[mt] = *(const bf16x8*)&As_[(wm + mt * 16 + r15) * 32 + kq * 8];
#pragma unroll
  for (int nt = 0; nt < 4; ++nt)
    bfv[nt] = *(const bf16x8*)&Bs_[(wn + nt * 16 + r15) * 32 + kq * 8];
#pragma unroll
  for (int mt = 0; mt < 2; ++mt)
#pragma unroll
    for (int nt = 0; nt < 4; ++nt)
      acc[mt][nt] = __builtin_amdgcn_mfma_f32_16x16x32_bf16(af[mt], bfv[nt], acc[mt][nt], 0, 0, 0);
}

__global__ __launch_bounds__(256) void convmm_kernel(const unsigned short* __restrict__ Aw,
                                                     const unsigned short* __restrict__ catp,
                                                     const float* __restrict__ cor,
                                                     float* __restrict__ y) {
  int ntile = blockIdx.x;
  int n = ntile >> 3, y0 = (ntile & 7) * 4;
  int m0 = blockIdx.y * 64;
  int t = threadIdx.x;
  int lane = t & 63, wv = t >> 6;
  int wm = (wv & 1) * 32, wn = (wv >> 1) * 64;

  // A: [buf][chunk][64 rows][32 k] = 16 KB;  B: [buf][chunk][128 px][32 k] = 32 KB
  __shared__ short Asm[2 * 2 * 64 * 32];
  __shared__ short Bsm[2 * 2 * 128 * 32];

  int idx0 = t, idx1 = t + 256;
  int ar0 = idx0 >> 2, aq0 = (idx0 & 3) ^ ((ar0 >> 1) & 3);
  int ar1 = idx1 >> 2, aq1 = (idx1 & 3) ^ ((ar1 >> 1) & 3);
  size_t abase0 = (size_t)(m0 + ar0) * 2304 + aq0 * 8;
  size_t bbase0 = ((size_t)n * 1156 + (size_t)(y0 + (ar0 >> 5)) * 34 + (ar0 & 31)) * 256 + aq0 * 8;
  size_t bbase1 = ((size_t)n * 1156 + (size_t)(y0 + (ar1 >> 5)) * 34 + (ar1 & 31)) * 256 + aq1 * 8;
  char* ldsA = (char*)Asm;
  char* ldsB = (char*)Bsm;
  int wvoff = wv * 1024;

  int r15 = lane & 15, kg = lane >> 4;
  int kq = kg ^ ((r15 >> 1) & 3);

  f32x4 acc[2][4];
#pragma unroll
  for (int i = 0; i < 2; ++i)
#pragma unroll
    for (int j = 0; j < 4; ++j) acc[i][j] = (f32x4){0.f, 0.f, 0.f, 0.f};

  // prologue: stage tile 0 into buffer 0
  conv_stage(Aw, catp, abase0, bbase0, bbase1, 0, ldsA, ldsB, wvoff);
  __syncthreads();

#pragma unroll 2
  for (int s = 0; s < 36; ++s) {
    char* la = ldsA + (s & 1) * 8192;
    char* lb = ldsB + (s & 1) * 16384;
    if (s < 35)
      conv_stage(Aw, catp, abase0, bbase0, bbase1, s + 1,
                 ldsA + ((s + 1) & 1) * 8192, ldsB + ((s + 1) & 1) * 16384, wvoff);
    conv_comp((const short*)la,          (const short*)lb,          wm, wn, r15, kq, acc);
    conv_comp((const short*)(la + 4096), (const short*)(lb + 8192), wm, wn, r15, kq, acc);
    __syncthreads();   // drains vmcnt(0): next tile staged; all waves done reading cur buf
  }

  int pixbase = (ntile & 7) * 128 + wn + (lane & 15);
  int ocbase = m0 + wm + (lane >> 4) * 4;
#pragma unroll
  for (int mt = 0; mt < 2; ++mt)
#pragma unroll
    for (int nt = 0; nt < 4; ++nt) {
      int oc = ocbase + mt * 16;
      int pix = pixbase + nt * 16;
      int py = pix >> 5, px = pix & 31;
      int yc = (py == 0) ? 0 : ((py == 31) ? 2 : 1);
      int xc = (px == 0) ? 0 : ((px == 31) ? 2 : 1);
      const float* cp = cor + ((size_t)n * 512 + oc) * 9 + yc * 3 + xc;
      float* yp = y + ((size_t)n * 512 + oc) * 1024 + pix;
#pragma unroll
      for (int r = 0; r < 4; ++r) yp[(size_t)r * 1024] = acc[mt][nt][r] + cp[(size_t)r * 9];
    }
}

// ---------------- BN batch stats per channel ----------------
__global__ __launch_bounds__(256) void bnstat_kernel(const float* __restrict__ y,
                                                     const float* __restrict__ bn_scale,
                                                     const float* __restrict__ bn_bias,
                                                     float* __restrict__ stats) {
  int oc = blockIdx.x, t = threadIdx.x;
  float s = 0.f, ss = 0.f;
  for (int n = 0; n < 16; ++n) {
    float4 v = ((const float4*)(y + ((size_t)n * 512 + oc) * 1024))[t];
    s  += v.x + v.y + v.z + v.w;
    ss += v.x * v.x + v.y * v.y + v.z * v.z + v.w * v.w;
  }
  for (int o = 32; o > 0; o >>= 1) {
    s  += __shfl_down(s, o);
    ss += __shfl_down(ss, o);
  }
  __shared__ float rs[4], rss[4];
  if ((t & 63) == 0) { rs[t >> 6] = s; rss[t >> 6] = ss; }
  __syncthreads();
  if (t == 0) {
    float S = rs[0] + rs[1] + rs[2] + rs[3];
    float SS = rss[0] + rss[1] + rss[2] + rss[3];
    float mean = S * (1.f / 16384.f);
    float var = SS * (1.f / 16384.f) - mean * mean;
    float se = bn_scale[oc] / sqrtf(var + 1e-5f);
    stats[oc * 2] = se;
    stats[oc * 2 + 1] = bn_bias[oc] - mean * se;
  }
}

// ---------------- normalize + relu + gamma*y + x ----------------
__global__ __launch_bounds__(256) void final_kernel(const float* __restrict__ y,
                                                    const float* __restrict__ x,
                                                    const float* __restrict__ stats,
                                                    const float* __restrict__ gamma,
                                                    float* __restrict__ outp) {
  int b = blockIdx.x;
  int c = b & 511;
  int t = threadIdx.x;
  float se = stats[c * 2], sh = stats[c * 2 + 1], g = gamma[0];
  float4 yv = ((const float4*)(y + (size_t)b * 1024))[t];
  float4 xv = ((const float4*)(x + (size_t)b * 1024))[t];
  float4 o;
  o.x = g * fmaxf(yv.x * se + sh, 0.f) + xv.x;
  o.y = g * fmaxf(yv.y * se + sh, 0.f) + xv.y;
  o.z = g * fmaxf(yv.z * se + sh, 0.f) + xv.z;
  o.w = g * fmaxf(yv.w * se + sh, 0.f) + xv.w;
  ((float4*)(outp + (size_t)b * 1024))[t] = o;
}

extern "C" void kernel_launch(void* const* d_in, const int* in_sizes, int n_in,
                              void* d_out, int out_size, void* d_ws, size_t ws_size,
                              hipStream_t stream) {
  const float* x        = (const float*)d_in[0];
  const float* rce_w    = (const float*)d_in[1];
  const float* rce_b    = (const float*)d_in[2];
  const float* q_w      = (const float*)d_in[3];
  const float* q_b      = (const float*)d_in[4];
  const float* k_w      = (const float*)d_in[5];
  const float* k_b      = (const float*)d_in[6];
  const float* value_w  = (const float*)d_in[7];
  const float* value_b  = (const float*)d_in[8];
  const float* fw       = (const float*)d_in[9];
  const float* bn_scale = (const float*)d_in[10];
  const float* bn_bias  = (const float*)d_in[11];
  const float* gamma    = (const float*)d_in[12];

  float* ws    = (float*)d_ws;
  float* cor   = ws + OFF_COR;
  unsigned short* pvh = (unsigned short*)(ws + OFF_PVH);
  float* ybuf  = ws + OFF_Y;
  unsigned short* xTbuf = (unsigned short*)(ws + OFF_Y);  // union: dead before convmm
  unsigned short* catp = (unsigned short*)(ws + OFF_CATP);
  unsigned short* qh   = (unsigned short*)(ws + OFF_QH);
  unsigned short* kh   = (unsigned short*)(ws + OFF_KH);
  float* pool  = ws + OFF_POOL;
  float* feat  = ws + OFF_FEAT;
  unsigned short* Aw = (unsigned short*)(ws + OFF_AW);
  float* means = ws + OFF_MEANS;
  float* stats = ws + OFF_STAT;
  unsigned short* vwh = (unsigned short*)(ws + OFF_VWH);
  float* outp  = (float*)d_out;

  hipLaunchKernelGGL(pool_kernel,    dim3(8192),       dim3(256), 0, stream, x, pool);
  hipLaunchKernelGGL(feat_kernel,    dim3(128, 16),    dim3(64),  0, stream, pool, rce_w, rce_b, feat);
  hipLaunchKernelGGL(qk2_kernel,     dim3(16),         dim3(256), 0, stream, feat, q_w, q_b, k_w, k_b, qh, kh);
  hipLaunchKernelGGL(xcast_kernel,   dim3(16, 8, 16),  dim3(256), 0, stream, x, xTbuf);
  hipLaunchKernelGGL(vwcast_kernel,  dim3(256),        dim3(256), 0, stream, value_w, vwh);
  hipLaunchKernelGGL(pvmm2_kernel,   dim3(16, 16),     dim3(256), 0, stream, vwh, xTbuf, value_b, pvh);
  hipLaunchKernelGGL(mean_kernel,    dim3(128, 16),    dim3(256), 0, stream, pvh, means);
  hipLaunchKernelGGL(basecor_kernel, dim3(512, 16),    dim3(64),  0, stream, means, fw, cor);
  hipLaunchKernelGGL(fillcat_kernel, dim3(2112),       dim3(128), 0, stream, catp);
  hipLaunchKernelGGL(wcast_kernel,   dim3(512),        dim3(256), 0, stream, fw, Aw);
  hipLaunchKernelGGL(fattn_kernel,   dim3(16, 16, 2),  dim3(256), 0, stream, qh, kh, pvh, catp);
  hipLaunchKernelGGL(convmm_kernel,  dim3(128, 8),     dim3(256), 0, stream, Aw, catp, cor, ybuf);
  hipLaunchKernelGGL(bnstat_kernel,  dim3(512),        dim3(256), 0, stream, ybuf, bn_scale, bn_bias, stats);
  hipLaunchKernelGGL(final_kernel,   dim3(8192),       dim3(256), 0, stream, ybuf, x, stats, gamma, outp);
}

// Round 7
// 244.612 us; speedup vs baseline: 1.2993x; 1.1349x over previous
//
#include <hip/hip_runtime.h>
#include <hip/hip_fp16.h>
#include <math.h>

// n=16, C=512, c4=128, qk=16, H=W=32, L=1024. fp32 in/out.
// conv (K=2304, mean-channels factored out analytically) + fused flash attention
// + value-proj, all matmuls on MFMA.
//
// ws layout (float offsets):
#define OFF_COR   0u          // cor   [16][512][9] f32 (mean-channel conv contribution)
#define OFF_PVH   2097152u    // pvh   [16][128][1024] f16
#define OFF_Y     3145728u    // y     [16][512][1024] f32
                              //   UNION: xT f16 [16][1024][512] (dead before convmm)
#define OFF_CATP  11534336u   // catT_p[16][1156][256] bf16 (pixel-major, 34x34 zero-padded)
#define OFF_QH    15085568u   // qh    [2][16][1024][16] f16
#define OFF_KH    15347712u   // kh    [2][16][1024][16] f16
#define OFF_POOL  16134144u   // pool  [16][512][20] f32
#define OFF_FEAT  16297984u   // feat  [16][128][20] f32
#define OFF_AW    16338944u   // Aw    [512][2304] bf16 (k = (ky*3+kx)*256 + (ic-128))
#define OFF_MEANS 17223680u   // means [16][128] f32
#define OFF_STAT  17225728u   // stats [512][2] f32
#define OFF_VWH   17226752u   // vwh   [128][512] f16

typedef __bf16 bf16x8 __attribute__((ext_vector_type(8)));
typedef _Float16 f16x8 __attribute__((ext_vector_type(8)));
typedef _Float16 f16x4 __attribute__((ext_vector_type(4)));
typedef float f32x4 __attribute__((ext_vector_type(4)));

__device__ __forceinline__ unsigned short f2bf(float f) {
  unsigned int u = __float_as_uint(f);
  unsigned int r = u + 0x7fff + ((u >> 16) & 1);   // RNE
  return (unsigned short)(r >> 16);
}

__device__ __forceinline__ unsigned short f2h(float f) {
  union { _Float16 h; unsigned short u; } cv;
  cv.h = (_Float16)f;
  return cv.u;
}

__device__ __forceinline__ void gload_lds16(const void* g, void* l) {
  __builtin_amdgcn_global_load_lds(
      (const __attribute__((address_space(1))) unsigned int*)g,
      (__attribute__((address_space(3))) unsigned int*)l, 16, 0, 0);
}

// ---------------- pooling: pooled4 (8x8 blocks) + pooled2 derived ----------------
__global__ __launch_bounds__(256) void pool_kernel(const float* __restrict__ x,
                                                   float* __restrict__ pool) {
  int b = blockIdx.x;            // n*512 + c
  int t = threadIdx.x;
  const float4* xp = (const float4*)(x + (size_t)b * 1024);
  float4 v = xp[t];
  float s4 = v.x + v.y + v.z + v.w;
  __shared__ float sm[256];
  __shared__ float p4s[16];
  sm[t] = s4;
  __syncthreads();
  if (t < 16) {
    int br = t >> 2, bc = t & 3;
    float s = 0.f;
#pragma unroll
    for (int rr = 0; rr < 8; ++rr) {
      int base = br * 64 + rr * 8 + bc * 2;
      s += sm[base] + sm[base + 1];
    }
    s *= (1.f / 64.f);
    p4s[t] = s;
    pool[(size_t)b * 20 + t] = s;
  }
  __syncthreads();
  if (t < 4) {
    int i2 = t >> 1, j2 = t & 1;
    float s = (p4s[(2*i2)*4 + 2*j2]     + p4s[(2*i2)*4 + 2*j2 + 1] +
               p4s[(2*i2+1)*4 + 2*j2]   + p4s[(2*i2+1)*4 + 2*j2 + 1]) * 0.25f;
    pool[(size_t)b * 20 + 16 + t] = s;
  }
}

// ---------------- feat = rce_w[i] @ pooled_i + rce_b[i] (scales sz=2,4) ----------------
__global__ __launch_bounds__(64) void feat_kernel(const float* __restrict__ pool,
                                                  const float* __restrict__ rce_w,
                                                  const float* __restrict__ rce_b,
                                                  float* __restrict__ feat) {
  int o = blockIdx.x, n = blockIdx.y, t = threadIdx.x;
  float part[20];
#pragma unroll
  for (int j = 0; j < 20; ++j) part[j] = 0.f;
  for (int c = t; c < 512; c += 64) {
    const float* pl = pool + ((size_t)n * 512 + c) * 20;
    float w2 = rce_w[(size_t)(128 + o) * 512 + c];
    float w4 = rce_w[(size_t)(256 + o) * 512 + c];
#pragma unroll
    for (int j = 0; j < 4; ++j)  part[j]     += w2 * pl[16 + j];
#pragma unroll
    for (int j = 0; j < 16; ++j) part[4 + j] += w4 * pl[j];
  }
  __shared__ float red[64][20];
#pragma unroll
  for (int j = 0; j < 20; ++j) red[t][j] = part[j];
  __syncthreads();
  if (t < 20) {
    float s = 0.f;
    for (int i = 0; i < 64; ++i) s += red[i][t];
    s += (t < 4) ? rce_b[128 + o] : rce_b[256 + o];
    feat[((size_t)n * 128 + o) * 20 + t] = s;
  }
}

// ------------- q/k fields, f16, layout [s][n][l][16] for MFMA attention -------------
// grid (16 n, 8 slices): GH recompute per block is cheap; the 4096-row upsample
// phase gets 8x the parallelism (was 16 blocks on a 256-CU chip).
__global__ __launch_bounds__(256) void qk2_kernel(const float* __restrict__ feat,
                                                  const float* __restrict__ q_w,
                                                  const float* __restrict__ q_b,
                                                  const float* __restrict__ k_w,
                                                  const float* __restrict__ k_b,
                                                  unsigned short* __restrict__ qh,
                                                  unsigned short* __restrict__ kh) {
  int n = blockIdx.x, t = threadIdx.x;
  __shared__ float fL[128 * 20];
  __shared__ float GH[2][16][20];
  for (int idx = t; idx < 2560; idx += 256) fL[idx] = feat[(size_t)n * 2560 + idx];
  __syncthreads();
  for (int idx = t; idx < 640; idx += 256) {
    int which = idx / 320, rem = idx % 320, qc = rem / 20, j = rem % 20;
    const float* w = which ? k_w : q_w;
    float s = which ? k_b[qc] : q_b[qc];
    for (int c = 0; c < 128; ++c) s += w[qc * 128 + c] * fL[c * 20 + j];
    GH[which][qc][j] = s;
  }
  __syncthreads();
  for (int it = blockIdx.y * 2; it < blockIdx.y * 2 + 2; ++it) {
    int row = t + 256 * it;              // 4096 rows: [s][which][l]
    int l = row & 1023, which = (row >> 10) & 1, s = row >> 11;
    int ry = l >> 5, cx = l & 31;
    int t0, t1, t2, t3;
    float w0, w1, w2, w3;
    if (s == 0) {
      float a = ry * (1.0f / 31.0f), b = cx * (1.0f / 31.0f);
      t0 = 0; t1 = 1; t2 = 2; t3 = 3;
      w0 = (1.f - a) * (1.f - b); w1 = (1.f - a) * b;
      w2 = a * (1.f - b);         w3 = a * b;
    } else {
      float pr = ry * (3.0f / 31.0f);
      int lr = (int)pr; if (lr > 2) lr = 2;
      float fr = pr - (float)lr;
      float pc = cx * (3.0f / 31.0f);
      int lc = (int)pc; if (lc > 2) lc = 2;
      float fc = pc - (float)lc;
      int base = 4 + lr * 4 + lc;
      t0 = base; t1 = base + 1; t2 = base + 4; t3 = base + 5;
      w0 = (1.f - fr) * (1.f - fc); w1 = (1.f - fr) * fc;
      w2 = fr * (1.f - fc);         w3 = fr * fc;
    }
    float val[16];
#pragma unroll
    for (int qc = 0; qc < 16; ++qc) {
      const float* G = GH[which][qc];
      val[qc] = w0 * G[t0] + w1 * G[t1] + w2 * G[t2] + w3 * G[t3];
    }
    unsigned short* dst = (which ? kh : qh) + (((size_t)(s * 16 + n) * 1024 + l) * 16);
#pragma unroll
    for (int u = 0; u < 4; ++u)
      *(ushort4*)(dst + 4 * u) = make_ushort4(f2h(val[4*u]), f2h(val[4*u+1]),
                                              f2h(val[4*u+2]), f2h(val[4*u+3]));
  }
}

// ---------------- xT[n][l][c] = f16(x[n][c][l])  (LDS tile transpose) ----------------
__global__ __launch_bounds__(256) void xcast_kernel(const float* __restrict__ x,
                                                    unsigned short* __restrict__ xT) {
  int lt = blockIdx.x, ct = blockIdx.y, n = blockIdx.z;
  int l0 = lt * 64, c0 = ct * 64, t = threadIdx.x;
  __shared__ float tile[64 * 65];
#pragma unroll
  for (int i = 0; i < 16; ++i) {
    int idx = t + 256 * i;
    int c = idx >> 6, l = idx & 63;
    tile[c * 65 + l] = x[((size_t)n * 512 + c0 + c) * 1024 + l0 + l];
  }
  __syncthreads();
#pragma unroll
  for (int i = 0; i < 16; ++i) {
    int idx = t + 256 * i;
    int l = idx >> 6, c = idx & 63;
    xT[((size_t)n * 1024 + l0 + l) * 512 + c0 + c] = f2h(tile[c * 65 + l]);
  }
}

// ---------------- vwh = f16(value_w) ----------------
__global__ __launch_bounds__(256) void vwcast_kernel(const float* __restrict__ vw,
                                                     unsigned short* __restrict__ vwh) {
  int i = blockIdx.x * 256 + threadIdx.x;
  vwh[i] = f2h(vw[i]);
}

// ------------- value-proj GEMM (f16 MFMA): pvh[c,l] = f16(sum_k vwh[c,k] xT[n][l][k] + vb) -------------
__global__ __launch_bounds__(256) void pvmm2_kernel(const unsigned short* __restrict__ vwh,
                                                    const unsigned short* __restrict__ xT,
                                                    const float* __restrict__ vb,
                                                    unsigned short* __restrict__ pvh) {
  int l0 = blockIdx.x * 64;
  int n = blockIdx.y;
  int t = threadIdx.x, lane = t & 63, wv = t >> 6;
  int wm = (wv & 1) * 64, wn = (wv >> 1) * 32;

  __shared__ short Asm[128 * 32];
  __shared__ short Bsm[64 * 32];

  int ar0 = t >> 2,        aq0 = (t & 3) ^ ((ar0 >> 1) & 3);
  int idx1 = t + 256; int ar1 = idx1 >> 2, aq1 = (idx1 & 3) ^ ((ar1 >> 1) & 3);
  int br  = t >> 2,        bq  = (t & 3) ^ ((br >> 1) & 3);
  const unsigned short* Ab0 = vwh + (size_t)ar0 * 512 + aq0 * 8;
  const unsigned short* Ab1 = vwh + (size_t)ar1 * 512 + aq1 * 8;
  const unsigned short* Bb  = xT + ((size_t)n * 1024 + l0 + br) * 512 + bq * 8;
  char* ldsA = (char*)Asm;
  char* ldsB = (char*)Bsm;
  int wvoff = wv * 1024;
  int r15 = lane & 15, kg = lane >> 4;
  int kq = kg ^ ((r15 >> 1) & 3);

  f32x4 acc[4][2];
#pragma unroll
  for (int i = 0; i < 4; ++i)
#pragma unroll
    for (int j = 0; j < 2; ++j) acc[i][j] = (f32x4){0.f, 0.f, 0.f, 0.f};

  for (int k0 = 0; k0 < 512; k0 += 32) {
    __syncthreads();
    gload_lds16(Ab0 + k0, ldsA + wvoff);
    gload_lds16(Ab1 + k0, ldsA + 4096 + wvoff);
    gload_lds16(Bb + k0,  ldsB + wvoff);
    __syncthreads();
    f16x8 af[4], bfr[2];
#pragma unroll
    for (int mt2 = 0; mt2 < 4; ++mt2)
      af[mt2] = *(const f16x8*)&Asm[(wm + mt2 * 16 + r15) * 32 + kq * 8];
#pragma unroll
    for (int nt2 = 0; nt2 < 2; ++nt2)
      bfr[nt2] = *(const f16x8*)&Bsm[(wn + nt2 * 16 + r15) * 32 + kq * 8];
#pragma unroll
    for (int mt2 = 0; mt2 < 4; ++mt2)
#pragma unroll
      for (int nt2 = 0; nt2 < 2; ++nt2)
        acc[mt2][nt2] = __builtin_amdgcn_mfma_f32_16x16x32_f16(af[mt2], bfr[nt2], acc[mt2][nt2], 0, 0, 0);
  }

  int c_lo = wm + (lane >> 4) * 4;
  int l_lo = wn + (lane & 15);
#pragma unroll
  for (int mt2 = 0; mt2 < 4; ++mt2)
#pragma unroll
    for (int nt2 = 0; nt2 < 2; ++nt2) {
      int l = l0 + l_lo + nt2 * 16;
#pragma unroll
      for (int r = 0; r < 4; ++r) {
        int c = c_lo + mt2 * 16 + r;
        pvh[((size_t)n * 128 + c) * 1024 + l] = f2h(acc[mt2][nt2][r] + vb[c]);
      }
    }
}

// ---------------- means[n][c] = mean_l pvh[n][c][l]  (sz=1 branch is constant) ----------------
__global__ __launch_bounds__(256) void mean_kernel(const unsigned short* __restrict__ pvh,
                                                   float* __restrict__ means) {
  int c = blockIdx.x, n = blockIdx.y, t = threadIdx.x;
  f16x4 v = ((const f16x4*)(pvh + ((size_t)n * 128 + c) * 1024))[t];
  float s = (float)v[0] + (float)v[1] + (float)v[2] + (float)v[3];
  for (int o = 32; o > 0; o >>= 1) s += __shfl_down(s, o);
  __shared__ float wsum[4];
  if ((t & 63) == 0) wsum[t >> 6] = s;
  __syncthreads();
  if (t == 0) means[n * 128 + c] = (wsum[0] + wsum[1] + wsum[2] + wsum[3]) * (1.f / 1024.f);
}

// ---- basecor: cor[n][oc][a*3+b] = sum over valid taps of S[ky][kx],
//      S[ky][kx] = sum_{c<128} means[n][c] * fw[oc][c][ky][kx].
//      a/b: 0 = top/left edge (ky/kx=0 cut), 1 = interior, 2 = bottom/right edge.
__global__ __launch_bounds__(64) void basecor_kernel(const float* __restrict__ means,
                                                     const float* __restrict__ fw,
                                                     float* __restrict__ cor) {
  int oc = blockIdx.x, n = blockIdx.y, t = threadIdx.x;
  float S[9];
#pragma unroll
  for (int j = 0; j < 9; ++j) S[j] = 0.f;
  for (int c = t; c < 128; c += 64) {
    float m = means[n * 128 + c];
    const float* wp = fw + (size_t)oc * 3456 + c * 9;
#pragma unroll
    for (int j = 0; j < 9; ++j) S[j] += m * wp[j];
  }
  __shared__ float red[64][9];
  __shared__ float Sf[9];
#pragma unroll
  for (int j = 0; j < 9; ++j) red[t][j] = S[j];
  __syncthreads();
  if (t < 9) {
    float s = 0.f;
    for (int i = 0; i < 64; ++i) s += red[i][t];
    Sf[t] = s;
  }
  __syncthreads();
  if (t < 9) {
    int a = t / 3, b = t % 3;
    float s = 0.f;
#pragma unroll
    for (int ky = 0; ky < 3; ++ky) {
      if ((a == 0 && ky == 0) || (a == 2 && ky == 2)) continue;
#pragma unroll
      for (int kx = 0; kx < 3; ++kx) {
        if ((b == 0 && kx == 0) || (b == 2 && kx == 2)) continue;
        s += Sf[ky * 3 + kx];
      }
    }
    cor[((size_t)n * 512 + oc) * 9 + t] = s;
  }
}

// ---- fillcat: zero the 132 border rows of each image (256 ch each) ----
__global__ __launch_bounds__(128) void fillcat_kernel(unsigned short* __restrict__ catp) {
  int b = blockIdx.x;            // n*132 + e
  int n = b / 132, e = b % 132;
  int py, px;
  if (e < 34)       { py = 0;          px = e; }
  else if (e < 68)  { py = 33;         px = e - 34; }
  else if (e < 100) { py = e - 68 + 1; px = 0; }
  else              { py = e - 100 + 1; px = 33; }
  unsigned int* row = (unsigned int*)(catp + ((size_t)n * 1156 + py * 34 + px) * 256);
  row[threadIdx.x] = 0u;         // 128 threads x 4 B = 512 B = full row
}

// ---------------- weight reorder+cast: Aw[oc][seg*256 + (ic-128)] ----------------
__global__ __launch_bounds__(256) void wcast_kernel(const float* __restrict__ fw,
                                                    unsigned short* __restrict__ Aw) {
  int oc = blockIdx.x, t = threadIdx.x;
  for (int j = t; j < 2304; j += 256) {
    int seg = j >> 8, ic2 = j & 255;
    Aw[(size_t)oc * 2304 + j] = f2bf(fw[(size_t)oc * 3456 + (128 + ic2) * 9 + seg]);
  }
}

// ------------- fused flash attention (MFMA QK^T + MFMA PV, no P in HBM) -------------
// PV staging double-buffered with COUNTED vmcnt: per iter, kbf loads (oldest)
// -> stage tile it+1 (youngest) -> QK MFMA -> vmcnt(4)+lgkmcnt(0)+barrier
// (tile it resident, it+1 still in flight) -> PV MFMA -> barrier. The stage
// gets a full iteration to land instead of draining at the mid barrier.
__global__ __launch_bounds__(256) void fattn_kernel(const unsigned short* __restrict__ qh,
                                                    const unsigned short* __restrict__ kh,
                                                    const unsigned short* __restrict__ pvh,
                                                    unsigned short* __restrict__ catp) {
  int m0 = blockIdx.x * 64;
  int n = blockIdx.y, sc = blockIdx.z;
  int t = threadIdx.x, lane = t & 63, wv = t >> 6;
  int wc = (wv >> 1) * 64;      // c base (0/64)
  int wm2 = (wv & 1) * 32;      // m base within block tile (0/32)
  int r15 = lane & 15, kg = lane >> 4;
  int kq = kg ^ ((r15 >> 1) & 3);

  const unsigned short* qb  = qh + ((size_t)(sc * 16 + n) * 1024 + m0 + wv * 16) * 16;
  const unsigned short* kb  = kh + ((size_t)(sc * 16 + n) * 1024) * 16;
  const unsigned short* pvb = pvh + (size_t)n * 128 * 1024;

  __shared__ short PVs[2 * 2 * 128 * 32];   // [buf][ks][128][32] = 32 KB
  __shared__ _Float16 Us[64 * 72];
  __shared__ float rsum[64];

  f16x8 zf = {0, 0, 0, 0, 0, 0, 0, 0};
  f16x8 qa = (kg < 2) ? *(const f16x8*)(qb + r15 * 16 + kg * 8) : zf;

  int prow = t >> 2;
  int aq = (t & 3) ^ ((prow >> 1) & 3);
  const unsigned short* Pb0 = pvb + (size_t)prow * 1024 + aq * 8;
  const unsigned short* Pb1 = pvb + (size_t)(prow + 64) * 1024 + aq * 8;
  char* ldsPV = (char*)PVs;
  int wvoff = wv * 1024;

  f32x4 acc[4][2];
#pragma unroll
  for (int i = 0; i < 4; ++i)
#pragma unroll
    for (int j = 0; j < 2; ++j) acc[i][j] = (f32x4){0.f, 0.f, 0.f, 0.f};
  float rs[4] = {0.f, 0.f, 0.f, 0.f};

  // prologue: stage tile 0 into buf 0 (4 VMEM ops, stay in flight)
  gload_lds16(Pb0,      ldsPV + wvoff);
  gload_lds16(Pb1,      ldsPV + 4096 + wvoff);
  gload_lds16(Pb0 + 32, ldsPV + 8192 + wvoff);
  gload_lds16(Pb1 + 32, ldsPV + 12288 + wvoff);

  for (int it = 0; it < 16; ++it) {
    int cur = it & 1;
    int l0 = it * 64;
    // 1. this iter's K fragments (issued OLDEST among live VMEM)
    f16x8 kbf[4];
#pragma unroll
    for (int lt = 0; lt < 4; ++lt)
      kbf[lt] = (kg < 2)
        ? *(const f16x8*)(kb + (size_t)(l0 + lt * 16 + r15) * 16 + kg * 8) : zf;
    // 2. stage next PV tile into the other buffer (youngest 4 VMEM ops)
    if (it < 15) {
      char* dst = ldsPV + (cur ^ 1) * 16384 + wvoff;
      gload_lds16(Pb0 + l0 + 64, dst);
      gload_lds16(Pb1 + l0 + 64, dst + 4096);
      gload_lds16(Pb0 + l0 + 96, dst + 8192);
      gload_lds16(Pb1 + l0 + 96, dst + 12288);
    }
    // 3. QK^T (compiler waits retire kbf, leaving the 4 stage ops in flight)
    f32x4 sacc[4];
#pragma unroll
    for (int lt = 0; lt < 4; ++lt)
      sacc[lt] = __builtin_amdgcn_mfma_f32_16x16x32_f16(qa, kbf[lt], (f32x4){0.f,0.f,0.f,0.f}, 0, 0, 0);
    // 4. softmax numerator -> Us (LDS), row-sum partials
#pragma unroll
    for (int lt = 0; lt < 4; ++lt)
#pragma unroll
      for (int r = 0; r < 4; ++r) {
        float e = __expf(sacc[lt][r]);
        Us[(wv * 16 + kg * 4 + r) * 72 + lt * 16 + r15] = (_Float16)e;
        rs[r] += e;
      }
    // 5. tile `cur` resident (all VMEM except the 4 newest retired); Us visible
    asm volatile("s_waitcnt vmcnt(4) lgkmcnt(0)" ::: "memory");
    __builtin_amdgcn_s_barrier();
    __builtin_amdgcn_sched_barrier(0);
    // 6. PV MFMAs on PVs[cur] + Us
#pragma unroll
    for (int ks = 0; ks < 2; ++ks) {
      f16x8 bfr[2];
#pragma unroll
      for (int nt = 0; nt < 2; ++nt)
        bfr[nt] = *(const f16x8*)&Us[(wm2 + nt * 16 + r15) * 72 + ks * 32 + kg * 8];
#pragma unroll
      for (int ct = 0; ct < 4; ++ct) {
        f16x8 af = *(const f16x8*)&PVs[cur * 8192 + ks * 4096 + (wc + ct * 16 + r15) * 32 + kq * 8];
#pragma unroll
        for (int nt = 0; nt < 2; ++nt)
          acc[ct][nt] = __builtin_amdgcn_mfma_f32_16x16x32_f16(af, bfr[nt], acc[ct][nt], 0, 0, 0);
      }
    }
    // 7. all waves done reading PVs[cur] + Us before next iter overwrites
    asm volatile("s_waitcnt lgkmcnt(0)" ::: "memory");
    __builtin_amdgcn_s_barrier();
    __builtin_amdgcn_sched_barrier(0);
  }

#pragma unroll
  for (int r = 0; r < 4; ++r) {
    rs[r] += __shfl_xor(rs[r], 1);
    rs[r] += __shfl_xor(rs[r], 2);
    rs[r] += __shfl_xor(rs[r], 4);
    rs[r] += __shfl_xor(rs[r], 8);
  }
  if (r15 == 0) {
#pragma unroll
    for (int r = 0; r < 4; ++r) rsum[wv * 16 + kg * 4 + r] = rs[r];
  }
  __syncthreads();

#pragma unroll
  for (int nt = 0; nt < 2; ++nt) {
    float inv = 1.f / rsum[wm2 + nt * 16 + r15];
    int pix = m0 + wm2 + nt * 16 + r15;
    unsigned short* ob = catp + ((size_t)n * 1156 + ((pix >> 5) + 1) * 34 + (pix & 31) + 1) * 256
                       + sc * 128 + wc + kg * 4;
#pragma unroll
    for (int ct = 0; ct < 4; ++ct) {
      ushort4 o = make_ushort4(f2bf(acc[ct][nt][0] * inv), f2bf(acc[ct][nt][1] * inv),
                               f2bf(acc[ct][nt][2] * inv), f2bf(acc[ct][nt][3] * inv));
      *(ushort4*)(ob + ct * 16) = o;
    }
  }
}

// ---------------- fusion conv as implicit GEMM (bf16 MFMA, K=2304) ----------------
// R1-proven structure (best of 6 variants, 48.2 us): 128x128 tile, BK=64 double
// buffer, stage s+1 issued BEFORE compute(s), one __syncthreads per tile.
// mean-channel contribution added from cor[n][oc][3x3] in the epilogue.
__device__ __forceinline__ void conv_stage(const unsigned short* __restrict__ Aw,
                                           const unsigned short* __restrict__ catp,
                                           size_t abase0, size_t abase1,
                                           size_t bbase0, size_t bbase1,
                                           int s, char* la, char* lb, int wvoff) {
  int seg = s >> 2;                                  // k = s*64 .. s*64+63, all in one seg
  size_t akk  = (size_t)s * 64;
  size_t boff = (size_t)((seg / 3) * 34 + (seg % 3)) * 256 + (size_t)(s & 3) * 64;
  gload_lds16(Aw + abase0 + akk,          la + wvoff);
  gload_lds16(Aw + abase1 + akk,          la + 4096 + wvoff);
  gload_lds16(Aw + abase0 + akk + 32,     la + 8192 + wvoff);
  gload_lds16(Aw + abase1 + akk + 32,     la + 12288 + wvoff);
  gload_lds16(catp + bbase0 + boff,       lb + wvoff);
  gload_lds16(catp + bbase1 + boff,       lb + 4096 + wvoff);
  gload_lds16(catp + bbase0 + boff + 32,  lb + 8192 + wvoff);
  gload_lds16(catp + bbase1 + boff + 32,  lb + 12288 + wvoff);
}

__device__ __forceinline__ void conv_comp(const short* As_, const short* Bs_,
                                          int wm, int wn, int r15, int kq,
                                          f32x4 acc[4][4]) {
  bf16x8 af[4], bf[4];
#pragma unroll
  for (int mt = 0; mt < 4; ++mt)
    af[mt] = *(const bf16x8*)&As_[(wm + mt * 16 + r15) * 32 + kq * 8];
#pragma unroll
  for (int nt = 0; nt < 4; ++nt)
    bf[nt] = *(const bf16x8*)&Bs_[(wn + nt * 16 + r15) * 32 + kq * 8];
#pragma unroll
  for (int mt = 0; mt < 4; ++mt)
#pragma unroll
    for (int nt = 0; nt < 4; ++nt)
      acc[mt][nt] = __builtin_amdgcn_mfma_f32_16x16x32_bf16(af[mt], bf[nt], acc[mt][nt], 0, 0, 0);
}

__global__ __launch_bounds__(256) void convmm_kernel(const unsigned short* __restrict__ Aw,
                                                     const unsigned short* __restrict__ catp,
                                                     const float* __restrict__ cor,
                                                     float* __restrict__ y) {
  int ntile = blockIdx.x;
  int n = ntile >> 3, y0 = (ntile & 7) * 4;
  int m0 = blockIdx.y * 128;
  int t = threadIdx.x;
  int lane = t & 63, wv = t >> 6;
  int wm = (wv & 1) * 64, wn = (wv >> 1) * 64;

  // [buf][chunk][128 rows][32 k] shorts: 2 x 16 KB per tensor = 64 KB total
  __shared__ short Asm[2 * 2 * 128 * 32];
  __shared__ short Bsm[2 * 2 * 128 * 32];

  int idx0 = t, idx1 = t + 256;
  int ar0 = idx0 >> 2, aq0 = (idx0 & 3) ^ ((ar0 >> 1) & 3);
  int ar1 = idx1 >> 2, aq1 = (idx1 & 3) ^ ((ar1 >> 1) & 3);
  size_t abase0 = (size_t)(m0 + ar0) * 2304 + aq0 * 8;
  size_t abase1 = (size_t)(m0 + ar1) * 2304 + aq1 * 8;
  size_t bbase0 = ((size_t)n * 1156 + (size_t)(y0 + (ar0 >> 5)) * 34 + (ar0 & 31)) * 256 + aq0 * 8;
  size_t bbase1 = ((size_t)n * 1156 + (size_t)(y0 + (ar1 >> 5)) * 34 + (ar1 & 31)) * 256 + aq1 * 8;
  char* ldsA = (char*)Asm;
  char* ldsB = (char*)Bsm;
  int wvoff = wv * 1024;

  int r15 = lane & 15, kg = lane >> 4;
  int kq = kg ^ ((r15 >> 1) & 3);

  f32x4 acc[4][4];
#pragma unroll
  for (int i = 0; i < 4; ++i)
#pragma unroll
    for (int j = 0; j < 4; ++j) acc[i][j] = (f32x4){0.f, 0.f, 0.f, 0.f};

  // prologue: stage tile 0 into buffer 0
  conv_stage(Aw, catp, abase0, abase1, bbase0, bbase1, 0, ldsA, ldsB, wvoff);
  __syncthreads();

#pragma unroll 2
  for (int s = 0; s < 36; ++s) {
    char* la = ldsA + (s & 1) * 16384;
    char* lb = ldsB + (s & 1) * 16384;
    if (s < 35)
      conv_stage(Aw, catp, abase0, abase1, bbase0, bbase1, s + 1,
                 ldsA + ((s + 1) & 1) * 16384, ldsB + ((s + 1) & 1) * 16384, wvoff);
    conv_comp((const short*)la,          (const short*)lb,          wm, wn, r15, kq, acc);
    conv_comp((const short*)(la + 8192), (const short*)(lb + 8192), wm, wn, r15, kq, acc);
    __syncthreads();   // drains vmcnt(0): next tile staged; all waves done reading cur buf
  }

  int pixbase = (ntile & 7) * 128 + wn + (lane & 15);
  int ocbase = m0 + wm + (lane >> 4) * 4;
#pragma unroll
  for (int mt = 0; mt < 4; ++mt)
#pragma unroll
    for (int nt = 0; nt < 4; ++nt) {
      int oc = ocbase + mt * 16;
      int pix = pixbase + nt * 16;
      int py = pix >> 5, px = pix & 31;
      int yc = (py == 0) ? 0 : ((py == 31) ? 2 : 1);
      int xc = (px == 0) ? 0 : ((px == 31) ? 2 : 1);
      const float* cp = cor + ((size_t)n * 512 + oc) * 9 + yc * 3 + xc;
      float* yp = y + ((size_t)n * 512 + oc) * 1024 + pix;
#pragma unroll
      for (int r = 0; r < 4; ++r) yp[(size_t)r * 1024] = acc[mt][nt][r] + cp[(size_t)r * 9];
    }
}

// ---------------- BN batch stats per channel ----------------
__global__ __launch_bounds__(256) void bnstat_kernel(const float* __restrict__ y,
                                                     const float* __restrict__ bn_scale,
                                                     const float* __restrict__ bn_bias,
                                                     float* __restrict__ stats) {
  int oc = blockIdx.x, t = threadIdx.x;
  float s = 0.f, ss = 0.f;
  for (int n = 0; n < 16; ++n) {
    float4 v = ((const float4*)(y + ((size_t)n * 512 + oc) * 1024))[t];
    s  += v.x + v.y + v.z + v.w;
    ss += v.x * v.x + v.y * v.y + v.z * v.z + v.w * v.w;
  }
  for (int o = 32; o > 0; o >>= 1) {
    s  += __shfl_down(s, o);
    ss += __shfl_down(ss, o);
  }
  __shared__ float rs[4], rss[4];
  if ((t & 63) == 0) { rs[t >> 6] = s; rss[t >> 6] = ss; }
  __syncthreads();
  if (t == 0) {
    float S = rs[0] + rs[1] + rs[2] + rs[3];
    float SS = rss[0] + rss[1] + rss[2] + rss[3];
    float mean = S * (1.f / 16384.f);
    float var = SS * (1.f / 16384.f) - mean * mean;
    float se = bn_scale[oc] / sqrtf(var + 1e-5f);
    stats[oc * 2] = se;
    stats[oc * 2 + 1] = bn_bias[oc] - mean * se;
  }
}

// ---------------- normalize + relu + gamma*y + x ----------------
__global__ __launch_bounds__(256) void final_kernel(const float* __restrict__ y,
                                                    const float* __restrict__ x,
                                                    const float* __restrict__ stats,
                                                    const float* __restrict__ gamma,
                                                    float* __restrict__ outp) {
  int b = blockIdx.x;
  int c = b & 511;
  int t = threadIdx.x;
  float se = stats[c * 2], sh = stats[c * 2 + 1], g = gamma[0];
  float4 yv = ((const float4*)(y + (size_t)b * 1024))[t];
  float4 xv = ((const float4*)(x + (size_t)b * 1024))[t];
  float4 o;
  o.x = g * fmaxf(yv.x * se + sh, 0.f) + xv.x;
  o.y = g * fmaxf(yv.y * se + sh, 0.f) + xv.y;
  o.z = g * fmaxf(yv.z * se + sh, 0.f) + xv.z;
  o.w = g * fmaxf(yv.w * se + sh, 0.f) + xv.w;
  ((float4*)(outp + (size_t)b * 1024))[t] = o;
}

extern "C" void kernel_launch(void* const* d_in, const int* in_sizes, int n_in,
                              void* d_out, int out_size, void* d_ws, size_t ws_size,
                              hipStream_t stream) {
  const float* x        = (const float*)d_in[0];
  const float* rce_w    = (const float*)d_in[1];
  const float* rce_b    = (const float*)d_in[2];
  const float* q_w      = (const float*)d_in[3];
  const float* q_b      = (const float*)d_in[4];
  const float* k_w      = (const float*)d_in[5];
  const float* k_b      = (const float*)d_in[6];
  const float* value_w  = (const float*)d_in[7];
  const float* value_b  = (const float*)d_in[8];
  const float* fw       = (const float*)d_in[9];
  const float* bn_scale = (const float*)d_in[10];
  const float* bn_bias  = (const float*)d_in[11];
  const float* gamma    = (const float*)d_in[12];

  float* ws    = (float*)d_ws;
  float* cor   = ws + OFF_COR;
  unsigned short* pvh = (unsigned short*)(ws + OFF_PVH);
  float* ybuf  = ws + OFF_Y;
  unsigned short* xTbuf = (unsigned short*)(ws + OFF_Y);  // union: dead before convmm
  unsigned short* catp = (unsigned short*)(ws + OFF_CATP);
  unsigned short* qh   = (unsigned short*)(ws + OFF_QH);
  unsigned short* kh   = (unsigned short*)(ws + OFF_KH);
  float* pool  = ws + OFF_POOL;
  float* feat  = ws + OFF_FEAT;
  unsigned short* Aw = (unsigned short*)(ws + OFF_AW);
  float* means = ws + OFF_MEANS;
  float* stats = ws + OFF_STAT;
  unsigned short* vwh = (unsigned short*)(ws + OFF_VWH);
  float* outp  = (float*)d_out;

  hipLaunchKernelGGL(pool_kernel,    dim3(8192),       dim3(256), 0, stream, x, pool);
  hipLaunchKernelGGL(feat_kernel,    dim3(128, 16),    dim3(64),  0, stream, pool, rce_w, rce_b, feat);
  hipLaunchKernelGGL(qk2_kernel,     dim3(16, 8),      dim3(256), 0, stream, feat, q_w, q_b, k_w, k_b, qh, kh);
  hipLaunchKernelGGL(xcast_kernel,   dim3(16, 8, 16),  dim3(256), 0, stream, x, xTbuf);
  hipLaunchKernelGGL(vwcast_kernel,  dim3(256),        dim3(256), 0, stream, value_w, vwh);
  hipLaunchKernelGGL(pvmm2_kernel,   dim3(16, 16),     dim3(256), 0, stream, vwh, xTbuf, value_b, pvh);
  hipLaunchKernelGGL(mean_kernel,    dim3(128, 16),    dim3(256), 0, stream, pvh, means);
  hipLaunchKernelGGL(basecor_kernel, dim3(512, 16),    dim3(64),  0, stream, means, fw, cor);
  hipLaunchKernelGGL(fillcat_kernel, dim3(2112),       dim3(128), 0, stream, catp);
  hipLaunchKernelGGL(wcast_kernel,   dim3(512),        dim3(256), 0, stream, fw, Aw);
  hipLaunchKernelGGL(fattn_kernel,   dim3(16, 16, 2),  dim3(256), 0, stream, qh, kh, pvh, catp);
  hipLaunchKernelGGL(convmm_kernel,  dim3(128, 4),     dim3(256), 0, stream, Aw, catp, cor, ybuf);
  hipLaunchKernelGGL(bnstat_kernel,  dim3(512),        dim3(256), 0, stream, ybuf, bn_scale, bn_bias, stats);
  hipLaunchKernelGGL(final_kernel,   dim3(8192),       dim3(256), 0, stream, ybuf, x, stats, gamma, outp);
}

// Round 8
// 243.291 us; speedup vs baseline: 1.3064x; 1.0054x over previous
//
#include <hip/hip_runtime.h>
#include <hip/hip_fp16.h>
#include <math.h>

// n=16, C=512, c4=128, qk=16, H=W=32, L=1024. fp32 in/out.
// conv (K=2304, mean-channels factored out analytically) + fused flash attention
// + value-proj, all matmuls on MFMA.
//
// ws layout (float offsets):
#define OFF_COR   0u          // cor   [16][512][9] f32 (mean-channel conv contribution)
#define OFF_PVH   2097152u    // pvh   [16][128][1024] f16
#define OFF_Y     3145728u    // y     [16][512][1024] f32
                              //   UNION: xT f16 [16][1024][512] (dead before convmm)
#define OFF_CATP  11534336u   // catT_p[16][1156][256] bf16 (pixel-major, 34x34 zero-padded)
#define OFF_QH    15085568u   // qh    [2][16][1024][16] f16
#define OFF_KH    15347712u   // kh    [2][16][1024][16] f16
#define OFF_POOL  16134144u   // pool  [16][512][20] f32
#define OFF_FEAT  16297984u   // feat  [16][128][20] f32
#define OFF_AW    16338944u   // Aw    [512][2304] bf16 (k = (ky*3+kx)*256 + (ic-128))
#define OFF_MEANS 17223680u   // means [16][128] f32
#define OFF_STAT  17225728u   // stats [512][2] f32
#define OFF_VWH   17226752u   // vwh   [128][512] f16

typedef __bf16 bf16x8 __attribute__((ext_vector_type(8)));
typedef _Float16 f16x8 __attribute__((ext_vector_type(8)));
typedef _Float16 f16x4 __attribute__((ext_vector_type(4)));
typedef float f32x4 __attribute__((ext_vector_type(4)));

__device__ __forceinline__ unsigned short f2bf(float f) {
  unsigned int u = __float_as_uint(f);
  unsigned int r = u + 0x7fff + ((u >> 16) & 1);   // RNE
  return (unsigned short)(r >> 16);
}

__device__ __forceinline__ unsigned short f2h(float f) {
  union { _Float16 h; unsigned short u; } cv;
  cv.h = (_Float16)f;
  return cv.u;
}

__device__ __forceinline__ void gload_lds16(const void* g, void* l) {
  __builtin_amdgcn_global_load_lds(
      (const __attribute__((address_space(1))) unsigned int*)g,
      (__attribute__((address_space(3))) unsigned int*)l, 16, 0, 0);
}

// ---------------- pooling: pooled4 (8x8 blocks) + pooled2 derived ----------------
__global__ __launch_bounds__(256) void pool_kernel(const float* __restrict__ x,
                                                   float* __restrict__ pool) {
  int b = blockIdx.x;            // n*512 + c
  int t = threadIdx.x;
  const float4* xp = (const float4*)(x + (size_t)b * 1024);
  float4 v = xp[t];
  float s4 = v.x + v.y + v.z + v.w;
  __shared__ float sm[256];
  __shared__ float p4s[16];
  sm[t] = s4;
  __syncthreads();
  if (t < 16) {
    int br = t >> 2, bc = t & 3;
    float s = 0.f;
#pragma unroll
    for (int rr = 0; rr < 8; ++rr) {
      int base = br * 64 + rr * 8 + bc * 2;
      s += sm[base] + sm[base + 1];
    }
    s *= (1.f / 64.f);
    p4s[t] = s;
    pool[(size_t)b * 20 + t] = s;
  }
  __syncthreads();
  if (t < 4) {
    int i2 = t >> 1, j2 = t & 1;
    float s = (p4s[(2*i2)*4 + 2*j2]     + p4s[(2*i2)*4 + 2*j2 + 1] +
               p4s[(2*i2+1)*4 + 2*j2]   + p4s[(2*i2+1)*4 + 2*j2 + 1]) * 0.25f;
    pool[(size_t)b * 20 + 16 + t] = s;
  }
}

// ---------------- feat = rce_w[i] @ pooled_i + rce_b[i] (scales sz=2,4) ----------------
__global__ __launch_bounds__(64) void feat_kernel(const float* __restrict__ pool,
                                                  const float* __restrict__ rce_w,
                                                  const float* __restrict__ rce_b,
                                                  float* __restrict__ feat) {
  int o = blockIdx.x, n = blockIdx.y, t = threadIdx.x;
  float part[20];
#pragma unroll
  for (int j = 0; j < 20; ++j) part[j] = 0.f;
  for (int c = t; c < 512; c += 64) {
    const float* pl = pool + ((size_t)n * 512 + c) * 20;
    float w2 = rce_w[(size_t)(128 + o) * 512 + c];
    float w4 = rce_w[(size_t)(256 + o) * 512 + c];
#pragma unroll
    for (int j = 0; j < 4; ++j)  part[j]     += w2 * pl[16 + j];
#pragma unroll
    for (int j = 0; j < 16; ++j) part[4 + j] += w4 * pl[j];
  }
  __shared__ float red[64][20];
#pragma unroll
  for (int j = 0; j < 20; ++j) red[t][j] = part[j];
  __syncthreads();
  if (t < 20) {
    float s = 0.f;
    for (int i = 0; i < 64; ++i) s += red[i][t];
    s += (t < 4) ? rce_b[128 + o] : rce_b[256 + o];
    feat[((size_t)n * 128 + o) * 20 + t] = s;
  }
}

// ------------- q/k fields, f16, layout [s][n][l][16] for MFMA attention -------------
// grid (16 n, 8 slices): GH recompute per block is cheap; the 4096-row upsample
// phase gets 8x the parallelism (was 16 blocks on a 256-CU chip).
__global__ __launch_bounds__(256) void qk2_kernel(const float* __restrict__ feat,
                                                  const float* __restrict__ q_w,
                                                  const float* __restrict__ q_b,
                                                  const float* __restrict__ k_w,
                                                  const float* __restrict__ k_b,
                                                  unsigned short* __restrict__ qh,
                                                  unsigned short* __restrict__ kh) {
  int n = blockIdx.x, t = threadIdx.x;
  __shared__ float fL[128 * 20];
  __shared__ float GH[2][16][20];
  for (int idx = t; idx < 2560; idx += 256) fL[idx] = feat[(size_t)n * 2560 + idx];
  __syncthreads();
  for (int idx = t; idx < 640; idx += 256) {
    int which = idx / 320, rem = idx % 320, qc = rem / 20, j = rem % 20;
    const float* w = which ? k_w : q_w;
    float s = which ? k_b[qc] : q_b[qc];
    for (int c = 0; c < 128; ++c) s += w[qc * 128 + c] * fL[c * 20 + j];
    GH[which][qc][j] = s;
  }
  __syncthreads();
  for (int it = blockIdx.y * 2; it < blockIdx.y * 2 + 2; ++it) {
    int row = t + 256 * it;              // 4096 rows: [s][which][l]
    int l = row & 1023, which = (row >> 10) & 1, s = row >> 11;
    int ry = l >> 5, cx = l & 31;
    int t0, t1, t2, t3;
    float w0, w1, w2, w3;
    if (s == 0) {
      float a = ry * (1.0f / 31.0f), b = cx * (1.0f / 31.0f);
      t0 = 0; t1 = 1; t2 = 2; t3 = 3;
      w0 = (1.f - a) * (1.f - b); w1 = (1.f - a) * b;
      w2 = a * (1.f - b);         w3 = a * b;
    } else {
      float pr = ry * (3.0f / 31.0f);
      int lr = (int)pr; if (lr > 2) lr = 2;
      float fr = pr - (float)lr;
      float pc = cx * (3.0f / 31.0f);
      int lc = (int)pc; if (lc > 2) lc = 2;
      float fc = pc - (float)lc;
      int base = 4 + lr * 4 + lc;
      t0 = base; t1 = base + 1; t2 = base + 4; t3 = base + 5;
      w0 = (1.f - fr) * (1.f - fc); w1 = (1.f - fr) * fc;
      w2 = fr * (1.f - fc);         w3 = fr * fc;
    }
    float val[16];
#pragma unroll
    for (int qc = 0; qc < 16; ++qc) {
      const float* G = GH[which][qc];
      val[qc] = w0 * G[t0] + w1 * G[t1] + w2 * G[t2] + w3 * G[t3];
    }
    unsigned short* dst = (which ? kh : qh) + (((size_t)(s * 16 + n) * 1024 + l) * 16);
#pragma unroll
    for (int u = 0; u < 4; ++u)
      *(ushort4*)(dst + 4 * u) = make_ushort4(f2h(val[4*u]), f2h(val[4*u+1]),
                                              f2h(val[4*u+2]), f2h(val[4*u+3]));
  }
}

// ---------------- xT[n][l][c] = f16(x[n][c][l])  (LDS tile transpose) ----------------
__global__ __launch_bounds__(256) void xcast_kernel(const float* __restrict__ x,
                                                    unsigned short* __restrict__ xT) {
  int lt = blockIdx.x, ct = blockIdx.y, n = blockIdx.z;
  int l0 = lt * 64, c0 = ct * 64, t = threadIdx.x;
  __shared__ float tile[64 * 65];
#pragma unroll
  for (int i = 0; i < 16; ++i) {
    int idx = t + 256 * i;
    int c = idx >> 6, l = idx & 63;
    tile[c * 65 + l] = x[((size_t)n * 512 + c0 + c) * 1024 + l0 + l];
  }
  __syncthreads();
#pragma unroll
  for (int i = 0; i < 16; ++i) {
    int idx = t + 256 * i;
    int l = idx >> 6, c = idx & 63;
    xT[((size_t)n * 1024 + l0 + l) * 512 + c0 + c] = f2h(tile[c * 65 + l]);
  }
}

// ---- prep: fused vwcast + wcast + fillcat (3 dispatches -> 1, all independent) ----
__global__ __launch_bounds__(256) void prep_kernel(const float* __restrict__ fw,
                                                   const float* __restrict__ vw,
                                                   unsigned short* __restrict__ Aw,
                                                   unsigned short* __restrict__ vwh,
                                                   unsigned short* __restrict__ catp) {
  int b = blockIdx.x, t = threadIdx.x;
  if (b < 512) {
    // wcast: Aw[oc][seg*256 + (ic-128)]
    int oc = b;
    for (int j = t; j < 2304; j += 256) {
      int seg = j >> 8, ic2 = j & 255;
      Aw[(size_t)oc * 2304 + j] = f2bf(fw[(size_t)oc * 3456 + (128 + ic2) * 9 + seg]);
    }
  } else if (b < 768) {
    // vwcast: 128*512 = 65536 elements over 256 blocks
    int i = (b - 512) * 256 + t;
    vwh[i] = f2h(vw[i]);
  } else {
    // fillcat: zero the 2112 border rows (2 rows per block, 128 threads each)
    int e = (b - 768) * 2 + (t >> 7);
    int n = e / 132, r = e % 132;
    int py, px;
    if (r < 34)       { py = 0;           px = r; }
    else if (r < 68)  { py = 33;          px = r - 34; }
    else if (r < 100) { py = r - 68 + 1;  px = 0; }
    else              { py = r - 100 + 1; px = 33; }
    unsigned int* row = (unsigned int*)(catp + ((size_t)n * 1156 + py * 34 + px) * 256);
    row[t & 127] = 0u;       // 128 threads x 4 B = 512 B = full row
  }
}

// ------------- value-proj GEMM (f16 MFMA): pvh[c,l] = f16(sum_k vwh[c,k] xT[n][l][k] + vb) -------------
// R1-proven schedule applied: BK=64 double buffer, stage s+1 issued BEFORE
// compute(s), ONE __syncthreads per tile (was 16 steps x 2 barriers x vmcnt0).
__global__ __launch_bounds__(256) void pvmm2_kernel(const unsigned short* __restrict__ vwh,
                                                    const unsigned short* __restrict__ xT,
                                                    const float* __restrict__ vb,
                                                    unsigned short* __restrict__ pvh) {
  int l0 = blockIdx.x * 64;
  int n = blockIdx.y;
  int t = threadIdx.x, lane = t & 63, wv = t >> 6;
  int wm = (wv & 1) * 64, wn = (wv >> 1) * 32;

  __shared__ short Asm[2 * 2 * 128 * 32];   // [buf][chunk][128][32] = 32 KB
  __shared__ short Bsm[2 * 2 * 64 * 32];    // [buf][chunk][64][32]  = 16 KB

  int ar0 = t >> 2,        aq0 = (t & 3) ^ ((ar0 >> 1) & 3);
  int idx1 = t + 256; int ar1 = idx1 >> 2, aq1 = (idx1 & 3) ^ ((ar1 >> 1) & 3);
  int br  = t >> 2,        bq  = (t & 3) ^ ((br >> 1) & 3);
  const unsigned short* Ab0 = vwh + (size_t)ar0 * 512 + aq0 * 8;
  const unsigned short* Ab1 = vwh + (size_t)ar1 * 512 + aq1 * 8;
  const unsigned short* Bb  = xT + ((size_t)n * 1024 + l0 + br) * 512 + bq * 8;
  char* ldsA = (char*)Asm;
  char* ldsB = (char*)Bsm;
  int wvoff = wv * 1024;
  int r15 = lane & 15, kg = lane >> 4;
  int kq = kg ^ ((r15 >> 1) & 3);

  f32x4 acc[4][2];
#pragma unroll
  for (int i = 0; i < 4; ++i)
#pragma unroll
    for (int j = 0; j < 2; ++j) acc[i][j] = (f32x4){0.f, 0.f, 0.f, 0.f};

#define PV_STAGE(s, la, lb) do {                          \
    int k0_ = (s) * 64;                                   \
    gload_lds16(Ab0 + k0_,      (la) + wvoff);            \
    gload_lds16(Ab1 + k0_,      (la) + 4096 + wvoff);     \
    gload_lds16(Ab0 + k0_ + 32, (la) + 8192 + wvoff);     \
    gload_lds16(Ab1 + k0_ + 32, (la) + 12288 + wvoff);    \
    gload_lds16(Bb + k0_,       (lb) + wvoff);            \
    gload_lds16(Bb + k0_ + 32,  (lb) + 4096 + wvoff);     \
  } while (0)

  // prologue: stage tile 0 into buffer 0
  PV_STAGE(0, ldsA, ldsB);
  __syncthreads();

#pragma unroll 2
  for (int s = 0; s < 8; ++s) {
    char* la = ldsA + (s & 1) * 16384;
    char* lb = ldsB + (s & 1) * 8192;
    if (s < 7)
      PV_STAGE(s + 1, ldsA + ((s + 1) & 1) * 16384, ldsB + ((s + 1) & 1) * 8192);
#pragma unroll
    for (int c = 0; c < 2; ++c) {
      const short* As_ = (const short*)(la + c * 8192);
      const short* Bs_ = (const short*)(lb + c * 4096);
      f16x8 af[4], bfr[2];
#pragma unroll
      for (int mt2 = 0; mt2 < 4; ++mt2)
        af[mt2] = *(const f16x8*)&As_[(wm + mt2 * 16 + r15) * 32 + kq * 8];
#pragma unroll
      for (int nt2 = 0; nt2 < 2; ++nt2)
        bfr[nt2] = *(const f16x8*)&Bs_[(wn + nt2 * 16 + r15) * 32 + kq * 8];
#pragma unroll
      for (int mt2 = 0; mt2 < 4; ++mt2)
#pragma unroll
        for (int nt2 = 0; nt2 < 2; ++nt2)
          acc[mt2][nt2] = __builtin_amdgcn_mfma_f32_16x16x32_f16(af[mt2], bfr[nt2], acc[mt2][nt2], 0, 0, 0);
    }
    __syncthreads();   // drains vmcnt(0): next tile staged; all waves done reading cur buf
  }
#undef PV_STAGE

  int c_lo = wm + (lane >> 4) * 4;
  int l_lo = wn + (lane & 15);
#pragma unroll
  for (int mt2 = 0; mt2 < 4; ++mt2)
#pragma unroll
    for (int nt2 = 0; nt2 < 2; ++nt2) {
      int l = l0 + l_lo + nt2 * 16;
#pragma unroll
      for (int r = 0; r < 4; ++r) {
        int c = c_lo + mt2 * 16 + r;
        pvh[((size_t)n * 128 + c) * 1024 + l] = f2h(acc[mt2][nt2][r] + vb[c]);
      }
    }
}

// ---------------- means[n][c] = mean_l pvh[n][c][l]  (sz=1 branch is constant) ----------------
__global__ __launch_bounds__(256) void mean_kernel(const unsigned short* __restrict__ pvh,
                                                   float* __restrict__ means) {
  int c = blockIdx.x, n = blockIdx.y, t = threadIdx.x;
  f16x4 v = ((const f16x4*)(pvh + ((size_t)n * 128 + c) * 1024))[t];
  float s = (float)v[0] + (float)v[1] + (float)v[2] + (float)v[3];
  for (int o = 32; o > 0; o >>= 1) s += __shfl_down(s, o);
  __shared__ float wsum[4];
  if ((t & 63) == 0) wsum[t >> 6] = s;
  __syncthreads();
  if (t == 0) means[n * 128 + c] = (wsum[0] + wsum[1] + wsum[2] + wsum[3]) * (1.f / 1024.f);
}

// ---- basecor: cor[n][oc][a*3+b] = sum over valid taps of S[ky][kx],
//      S[ky][kx] = sum_{c<128} means[n][c] * fw[oc][c][ky][kx].
//      a/b: 0 = top/left edge (ky/kx=0 cut), 1 = interior, 2 = bottom/right edge.
__global__ __launch_bounds__(64) void basecor_kernel(const float* __restrict__ means,
                                                     const float* __restrict__ fw,
                                                     float* __restrict__ cor) {
  int oc = blockIdx.x, n = blockIdx.y, t = threadIdx.x;
  float S[9];
#pragma unroll
  for (int j = 0; j < 9; ++j) S[j] = 0.f;
  for (int c = t; c < 128; c += 64) {
    float m = means[n * 128 + c];
    const float* wp = fw + (size_t)oc * 3456 + c * 9;
#pragma unroll
    for (int j = 0; j < 9; ++j) S[j] += m * wp[j];
  }
  __shared__ float red[64][9];
  __shared__ float Sf[9];
#pragma unroll
  for (int j = 0; j < 9; ++j) red[t][j] = S[j];
  __syncthreads();
  if (t < 9) {
    float s = 0.f;
    for (int i = 0; i < 64; ++i) s += red[i][t];
    Sf[t] = s;
  }
  __syncthreads();
  if (t < 9) {
    int a = t / 3, b = t % 3;
    float s = 0.f;
#pragma unroll
    for (int ky = 0; ky < 3; ++ky) {
      if ((a == 0 && ky == 0) || (a == 2 && ky == 2)) continue;
#pragma unroll
      for (int kx = 0; kx < 3; ++kx) {
        if ((b == 0 && kx == 0) || (b == 2 && kx == 2)) continue;
        s += Sf[ky * 3 + kx];
      }
    }
    cor[((size_t)n * 512 + oc) * 9 + t] = s;
  }
}

// ------------- fused flash attention (MFMA QK^T + MFMA PV, no P in HBM) -------------
// PV staging double-buffered with COUNTED vmcnt: per iter, kbf loads (oldest)
// -> stage tile it+1 (youngest) -> QK MFMA -> vmcnt(4)+lgkmcnt(0)+barrier
// (tile it resident, it+1 still in flight) -> PV MFMA -> barrier. The stage
// gets a full iteration to land instead of draining at the mid barrier.
__global__ __launch_bounds__(256) void fattn_kernel(const unsigned short* __restrict__ qh,
                                                    const unsigned short* __restrict__ kh,
                                                    const unsigned short* __restrict__ pvh,
                                                    unsigned short* __restrict__ catp) {
  int m0 = blockIdx.x * 64;
  int n = blockIdx.y, sc = blockIdx.z;
  int t = threadIdx.x, lane = t & 63, wv = t >> 6;
  int wc = (wv >> 1) * 64;      // c base (0/64)
  int wm2 = (wv & 1) * 32;      // m base within block tile (0/32)
  int r15 = lane & 15, kg = lane >> 4;
  int kq = kg ^ ((r15 >> 1) & 3);

  const unsigned short* qb  = qh + ((size_t)(sc * 16 + n) * 1024 + m0 + wv * 16) * 16;
  const unsigned short* kb  = kh + ((size_t)(sc * 16 + n) * 1024) * 16;
  const unsigned short* pvb = pvh + (size_t)n * 128 * 1024;

  __shared__ short PVs[2 * 2 * 128 * 32];   // [buf][ks][128][32] = 32 KB
  __shared__ _Float16 Us[64 * 72];
  __shared__ float rsum[64];

  f16x8 zf = {0, 0, 0, 0, 0, 0, 0, 0};
  f16x8 qa = (kg < 2) ? *(const f16x8*)(qb + r15 * 16 + kg * 8) : zf;

  int prow = t >> 2;
  int aq = (t & 3) ^ ((prow >> 1) & 3);
  const unsigned short* Pb0 = pvb + (size_t)prow * 1024 + aq * 8;
  const unsigned short* Pb1 = pvb + (size_t)(prow + 64) * 1024 + aq * 8;
  char* ldsPV = (char*)PVs;
  int wvoff = wv * 1024;

  f32x4 acc[4][2];
#pragma unroll
  for (int i = 0; i < 4; ++i)
#pragma unroll
    for (int j = 0; j < 2; ++j) acc[i][j] = (f32x4){0.f, 0.f, 0.f, 0.f};
  float rs[4] = {0.f, 0.f, 0.f, 0.f};

  // prologue: stage tile 0 into buf 0 (4 VMEM ops, stay in flight)
  gload_lds16(Pb0,      ldsPV + wvoff);
  gload_lds16(Pb1,      ldsPV + 4096 + wvoff);
  gload_lds16(Pb0 + 32, ldsPV + 8192 + wvoff);
  gload_lds16(Pb1 + 32, ldsPV + 12288 + wvoff);

  for (int it = 0; it < 16; ++it) {
    int cur = it & 1;
    int l0 = it * 64;
    // 1. this iter's K fragments (issued OLDEST among live VMEM)
    f16x8 kbf[4];
#pragma unroll
    for (int lt = 0; lt < 4; ++lt)
      kbf[lt] = (kg < 2)
        ? *(const f16x8*)(kb + (size_t)(l0 + lt * 16 + r15) * 16 + kg * 8) : zf;
    // 2. stage next PV tile into the other buffer (youngest 4 VMEM ops)
    if (it < 15) {
      char* dst = ldsPV + (cur ^ 1) * 16384 + wvoff;
      gload_lds16(Pb0 + l0 + 64, dst);
      gload_lds16(Pb1 + l0 + 64, dst + 4096);
      gload_lds16(Pb0 + l0 + 96, dst + 8192);
      gload_lds16(Pb1 + l0 + 96, dst + 12288);
    }
    // 3. QK^T (compiler waits retire kbf, leaving the 4 stage ops in flight)
    f32x4 sacc[4];
#pragma unroll
    for (int lt = 0; lt < 4; ++lt)
      sacc[lt] = __builtin_amdgcn_mfma_f32_16x16x32_f16(qa, kbf[lt], (f32x4){0.f,0.f,0.f,0.f}, 0, 0, 0);
    // 4. softmax numerator -> Us (LDS), row-sum partials
#pragma unroll
    for (int lt = 0; lt < 4; ++lt)
#pragma unroll
      for (int r = 0; r < 4; ++r) {
        float e = __expf(sacc[lt][r]);
        Us[(wv * 16 + kg * 4 + r) * 72 + lt * 16 + r15] = (_Float16)e;
        rs[r] += e;
      }
    // 5. tile `cur` resident (all VMEM except the 4 newest retired); Us visible
    asm volatile("s_waitcnt vmcnt(4) lgkmcnt(0)" ::: "memory");
    __builtin_amdgcn_s_barrier();
    __builtin_amdgcn_sched_barrier(0);
    // 6. PV MFMAs on PVs[cur] + Us
#pragma unroll
    for (int ks = 0; ks < 2; ++ks) {
      f16x8 bfr[2];
#pragma unroll
      for (int nt = 0; nt < 2; ++nt)
        bfr[nt] = *(const f16x8*)&Us[(wm2 + nt * 16 + r15) * 72 + ks * 32 + kg * 8];
#pragma unroll
      for (int ct = 0; ct < 4; ++ct) {
        f16x8 af = *(const f16x8*)&PVs[cur * 8192 + ks * 4096 + (wc + ct * 16 + r15) * 32 + kq * 8];
#pragma unroll
        for (int nt = 0; nt < 2; ++nt)
          acc[ct][nt] = __builtin_amdgcn_mfma_f32_16x16x32_f16(af, bfr[nt], acc[ct][nt], 0, 0, 0);
      }
    }
    // 7. all waves done reading PVs[cur] + Us before next iter overwrites
    asm volatile("s_waitcnt lgkmcnt(0)" ::: "memory");
    __builtin_amdgcn_s_barrier();
    __builtin_amdgcn_sched_barrier(0);
  }

#pragma unroll
  for (int r = 0; r < 4; ++r) {
    rs[r] += __shfl_xor(rs[r], 1);
    rs[r] += __shfl_xor(rs[r], 2);
    rs[r] += __shfl_xor(rs[r], 4);
    rs[r] += __shfl_xor(rs[r], 8);
  }
  if (r15 == 0) {
#pragma unroll
    for (int r = 0; r < 4; ++r) rsum[wv * 16 + kg * 4 + r] = rs[r];
  }
  __syncthreads();

#pragma unroll
  for (int nt = 0; nt < 2; ++nt) {
    float inv = 1.f / rsum[wm2 + nt * 16 + r15];
    int pix = m0 + wm2 + nt * 16 + r15;
    unsigned short* ob = catp + ((size_t)n * 1156 + ((pix >> 5) + 1) * 34 + (pix & 31) + 1) * 256
                       + sc * 128 + wc + kg * 4;
#pragma unroll
    for (int ct = 0; ct < 4; ++ct) {
      ushort4 o = make_ushort4(f2bf(acc[ct][nt][0] * inv), f2bf(acc[ct][nt][1] * inv),
                               f2bf(acc[ct][nt][2] * inv), f2bf(acc[ct][nt][3] * inv));
      *(ushort4*)(ob + ct * 16) = o;
    }
  }
}

// ---------------- fusion conv as implicit GEMM (bf16 MFMA, K=2304) ----------------
// R1-proven structure (best of 6 variants, 48.2 us): 128x128 tile, BK=64 double
// buffer, stage s+1 issued BEFORE compute(s), one __syncthreads per tile.
// mean-channel contribution added from cor[n][oc][3x3] in the epilogue.
__device__ __forceinline__ void conv_stage(const unsigned short* __restrict__ Aw,
                                           const unsigned short* __restrict__ catp,
                                           size_t abase0, size_t abase1,
                                           size_t bbase0, size_t bbase1,
                                           int s, char* la, char* lb, int wvoff) {
  int seg = s >> 2;                                  // k = s*64 .. s*64+63, all in one seg
  size_t akk  = (size_t)s * 64;
  size_t boff = (size_t)((seg / 3) * 34 + (seg % 3)) * 256 + (size_t)(s & 3) * 64;
  gload_lds16(Aw + abase0 + akk,          la + wvoff);
  gload_lds16(Aw + abase1 + akk,          la + 4096 + wvoff);
  gload_lds16(Aw + abase0 + akk + 32,     la + 8192 + wvoff);
  gload_lds16(Aw + abase1 + akk + 32,     la + 12288 + wvoff);
  gload_lds16(catp + bbase0 + boff,       lb + wvoff);
  gload_lds16(catp + bbase1 + boff,       lb + 4096 + wvoff);
  gload_lds16(catp + bbase0 + boff + 32,  lb + 8192 + wvoff);
  gload_lds16(catp + bbase1 + boff + 32,  lb + 12288 + wvoff);
}

__device__ __forceinline__ void conv_comp(const short* As_, const short* Bs_,
                                          int wm, int wn, int r15, int kq,
                                          f32x4 acc[4][4]) {
  bf16x8 af[4], bf[4];
#pragma unroll
  for (int mt = 0; mt < 4; ++mt)
    af[mt] = *(const bf16x8*)&As_[(wm + mt * 16 + r15) * 32 + kq * 8];
#pragma unroll
  for (int nt = 0; nt < 4; ++nt)
    bf[nt] = *(const bf16x8*)&Bs_[(wn + nt * 16 + r15) * 32 + kq * 8];
#pragma unroll
  for (int mt = 0; mt < 4; ++mt)
#pragma unroll
    for (int nt = 0; nt < 4; ++nt)
      acc[mt][nt] = __builtin_amdgcn_mfma_f32_16x16x32_bf16(af[mt], bf[nt], acc[mt][nt], 0, 0, 0);
}

__global__ __launch_bounds__(256) void convmm_kernel(const unsigned short* __restrict__ Aw,
                                                     const unsigned short* __restrict__ catp,
                                                     const float* __restrict__ cor,
                                                     float* __restrict__ y) {
  int ntile = blockIdx.x;
  int n = ntile >> 3, y0 = (ntile & 7) * 4;
  int m0 = blockIdx.y * 128;
  int t = threadIdx.x;
  int lane = t & 63, wv = t >> 6;
  int wm = (wv & 1) * 64, wn = (wv >> 1) * 64;

  // [buf][chunk][128 rows][32 k] shorts: 2 x 16 KB per tensor = 64 KB total
  __shared__ short Asm[2 * 2 * 128 * 32];
  __shared__ short Bsm[2 * 2 * 128 * 32];

  int idx0 = t, idx1 = t + 256;
  int ar0 = idx0 >> 2, aq0 = (idx0 & 3) ^ ((ar0 >> 1) & 3);
  int ar1 = idx1 >> 2, aq1 = (idx1 & 3) ^ ((ar1 >> 1) & 3);
  size_t abase0 = (size_t)(m0 + ar0) * 2304 + aq0 * 8;
  size_t abase1 = (size_t)(m0 + ar1) * 2304 + aq1 * 8;
  size_t bbase0 = ((size_t)n * 1156 + (size_t)(y0 + (ar0 >> 5)) * 34 + (ar0 & 31)) * 256 + aq0 * 8;
  size_t bbase1 = ((size_t)n * 1156 + (size_t)(y0 + (ar1 >> 5)) * 34 + (ar1 & 31)) * 256 + aq1 * 8;
  char* ldsA = (char*)Asm;
  char* ldsB = (char*)Bsm;
  int wvoff = wv * 1024;

  int r15 = lane & 15, kg = lane >> 4;
  int kq = kg ^ ((r15 >> 1) & 3);

  f32x4 acc[4][4];
#pragma unroll
  for (int i = 0; i < 4; ++i)
#pragma unroll
    for (int j = 0; j < 4; ++j) acc[i][j] = (f32x4){0.f, 0.f, 0.f, 0.f};

  // prologue: stage tile 0 into buffer 0
  conv_stage(Aw, catp, abase0, abase1, bbase0, bbase1, 0, ldsA, ldsB, wvoff);
  __syncthreads();

#pragma unroll 2
  for (int s = 0; s < 36; ++s) {
    char* la = ldsA + (s & 1) * 16384;
    char* lb = ldsB + (s & 1) * 16384;
    if (s < 35)
      conv_stage(Aw, catp, abase0, abase1, bbase0, bbase1, s + 1,
                 ldsA + ((s + 1) & 1) * 16384, ldsB + ((s + 1) & 1) * 16384, wvoff);
    conv_comp((const short*)la,          (const short*)lb,          wm, wn, r15, kq, acc);
    conv_comp((const short*)(la + 8192), (const short*)(lb + 8192), wm, wn, r15, kq, acc);
    __syncthreads();   // drains vmcnt(0): next tile staged; all waves done reading cur buf
  }

  int pixbase = (ntile & 7) * 128 + wn + (lane & 15);
  int ocbase = m0 + wm + (lane >> 4) * 4;
#pragma unroll
  for (int mt = 0; mt < 4; ++mt)
#pragma unroll
    for (int nt = 0; nt < 4; ++nt) {
      int oc = ocbase + mt * 16;
      int pix = pixbase + nt * 16;
      int py = pix >> 5, px = pix & 31;
      int yc = (py == 0) ? 0 : ((py == 31) ? 2 : 1);
      int xc = (px == 0) ? 0 : ((px == 31) ? 2 : 1);
      const float* cp = cor + ((size_t)n * 512 + oc) * 9 + yc * 3 + xc;
      float* yp = y + ((size_t)n * 512 + oc) * 1024 + pix;
#pragma unroll
      for (int r = 0; r < 4; ++r) yp[(size_t)r * 1024] = acc[mt][nt][r] + cp[(size_t)r * 9];
    }
}

// ---------------- BN batch stats per channel ----------------
__global__ __launch_bounds__(256) void bnstat_kernel(const float* __restrict__ y,
                                                     const float* __restrict__ bn_scale,
                                                     const float* __restrict__ bn_bias,
                                                     float* __restrict__ stats) {
  int oc = blockIdx.x, t = threadIdx.x;
  float s = 0.f, ss = 0.f;
  for (int n = 0; n < 16; ++n) {
    float4 v = ((const float4*)(y + ((size_t)n * 512 + oc) * 1024))[t];
    s  += v.x + v.y + v.z + v.w;
    ss += v.x * v.x + v.y * v.y + v.z * v.z + v.w * v.w;
  }
  for (int o = 32; o > 0; o >>= 1) {
    s  += __shfl_down(s, o);
    ss += __shfl_down(ss, o);
  }
  __shared__ float rs[4], rss[4];
  if ((t & 63) == 0) { rs[t >> 6] = s; rss[t >> 6] = ss; }
  __syncthreads();
  if (t == 0) {
    float S = rs[0] + rs[1] + rs[2] + rs[3];
    float SS = rss[0] + rss[1] + rss[2] + rss[3];
    float mean = S * (1.f / 16384.f);
    float var = SS * (1.f / 16384.f) - mean * mean;
    float se = bn_scale[oc] / sqrtf(var + 1e-5f);
    stats[oc * 2] = se;
    stats[oc * 2 + 1] = bn_bias[oc] - mean * se;
  }
}

// ---------------- normalize + relu + gamma*y + x ----------------
__global__ __launch_bounds__(256) void final_kernel(const float* __restrict__ y,
                                                    const float* __restrict__ x,
                                                    const float* __restrict__ stats,
                                                    const float* __restrict__ gamma,
                                                    float* __restrict__ outp) {
  int b = blockIdx.x;
  int c = b & 511;
  int t = threadIdx.x;
  float se = stats[c * 2], sh = stats[c * 2 + 1], g = gamma[0];
  float4 yv = ((const float4*)(y + (size_t)b * 1024))[t];
  float4 xv = ((const float4*)(x + (size_t)b * 1024))[t];
  float4 o;
  o.x = g * fmaxf(yv.x * se + sh, 0.f) + xv.x;
  o.y = g * fmaxf(yv.y * se + sh, 0.f) + xv.y;
  o.z = g * fmaxf(yv.z * se + sh, 0.f) + xv.z;
  o.w = g * fmaxf(yv.w * se + sh, 0.f) + xv.w;
  ((float4*)(outp + (size_t)b * 1024))[t] = o;
}

extern "C" void kernel_launch(void* const* d_in, const int* in_sizes, int n_in,
                              void* d_out, int out_size, void* d_ws, size_t ws_size,
                              hipStream_t stream) {
  const float* x        = (const float*)d_in[0];
  const float* rce_w    = (const float*)d_in[1];
  const float* rce_b    = (const float*)d_in[2];
  const float* q_w      = (const float*)d_in[3];
  const float* q_b      = (const float*)d_in[4];
  const float* k_w      = (const float*)d_in[5];
  const float* k_b      = (const float*)d_in[6];
  const float* value_w  = (const float*)d_in[7];
  const float* value_b  = (const float*)d_in[8];
  const float* fw       = (const float*)d_in[9];
  const float* bn_scale = (const float*)d_in[10];
  const float* bn_bias  = (const float*)d_in[11];
  const float* gamma    = (const float*)d_in[12];

  float* ws    = (float*)d_ws;
  float* cor   = ws + OFF_COR;
  unsigned short* pvh = (unsigned short*)(ws + OFF_PVH);
  float* ybuf  = ws + OFF_Y;
  unsigned short* xTbuf = (unsigned short*)(ws + OFF_Y);  // union: dead before convmm
  unsigned short* catp = (unsigned short*)(ws + OFF_CATP);
  unsigned short* qh   = (unsigned short*)(ws + OFF_QH);
  unsigned short* kh   = (unsigned short*)(ws + OFF_KH);
  float* pool  = ws + OFF_POOL;
  float* feat  = ws + OFF_FEAT;
  unsigned short* Aw = (unsigned short*)(ws + OFF_AW);
  float* means = ws + OFF_MEANS;
  float* stats = ws + OFF_STAT;
  unsigned short* vwh = (unsigned short*)(ws + OFF_VWH);
  float* outp  = (float*)d_out;

  hipLaunchKernelGGL(pool_kernel,    dim3(8192),       dim3(256), 0, stream, x, pool);
  hipLaunchKernelGGL(feat_kernel,    dim3(128, 16),    dim3(64),  0, stream, pool, rce_w, rce_b, feat);
  hipLaunchKernelGGL(qk2_kernel,     dim3(16, 8),      dim3(256), 0, stream, feat, q_w, q_b, k_w, k_b, qh, kh);
  hipLaunchKernelGGL(xcast_kernel,   dim3(16, 8, 16),  dim3(256), 0, stream, x, xTbuf);
  hipLaunchKernelGGL(prep_kernel,    dim3(1824),       dim3(256), 0, stream, fw, value_w, Aw, vwh, catp);
  hipLaunchKernelGGL(pvmm2_kernel,   dim3(16, 16),     dim3(256), 0, stream, vwh, xTbuf, value_b, pvh);
  hipLaunchKernelGGL(mean_kernel,    dim3(128, 16),    dim3(256), 0, stream, pvh, means);
  hipLaunchKernelGGL(basecor_kernel, dim3(512, 16),    dim3(64),  0, stream, means, fw, cor);
  hipLaunchKernelGGL(fattn_kernel,   dim3(16, 16, 2),  dim3(256), 0, stream, qh, kh, pvh, catp);
  hipLaunchKernelGGL(convmm_kernel,  dim3(128, 4),     dim3(256), 0, stream, Aw, catp, cor, ybuf);
  hipLaunchKernelGGL(bnstat_kernel,  dim3(512),        dim3(256), 0, stream, ybuf, bn_scale, bn_bias, stats);
  hipLaunchKernelGGL(final_kernel,   dim3(8192),       dim3(256), 0, stream, ybuf, x, stats, gamma, outp);
}